// Round 6
// baseline (633.363 us; speedup 1.0000x reference)
//
#include <hip/hip_runtime.h>
#include <hip/hip_bf16.h>
#include <math.h>

#define B     8
#define S     512
#define MEM   512
#define L     4
#define E     512
#define H     8
#define DH    64
#define OBS   128
#define KLEN  1024   // MEM + S
#define FQ    64     // flash: q rows per block
#define FK    64     // flash: k per tile

typedef __hip_bfloat16 bf16;
using frag_ab = __attribute__((ext_vector_type(8))) short;   // 8 bf16 (4 VGPRs)
using frag_cd = __attribute__((ext_vector_type(4))) float;   // 4 fp32 acc

__device__ __forceinline__ float gelu_tanh(float x) {
    return 0.5f * x * (1.0f + tanhf(0.7978845608028654f * (x + 0.044715f * x * x * x)));
}
__device__ __forceinline__ unsigned short f2bs(float x) {
    bf16 h = __float2bfloat16(x); return *(unsigned short*)&h;
}
__device__ __forceinline__ float bs2f(short s) {
    union { unsigned u; float f; } t; t.u = ((unsigned)(unsigned short)s) << 16; return t.f;
}

// ---------------- merged setup: obs cast + positional embedding --------------
__global__ __launch_bounds__(256) void setup_kernel(
    const float* __restrict__ obs, bf16* __restrict__ obsb, bf16* __restrict__ pe)
{
    const int i = blockIdx.x * 256 + threadIdx.x;
    if (i < B * S * OBS) {
        obsb[i] = __float2bfloat16(obs[i]);
    } else {
        const int idx = i - B * S * OBS;
        const int p = idx >> 9;
        const int j = idx & 511;
        const float pos = (float)(KLEN - p);
        const int m = (j < 256) ? j : (j - 256);
        const float invf = expf(-(float)(2 * m) * (9.210340371976184f / (float)E));
        const float a = pos * invf;
        pe[idx] = __float2bfloat16((j < 256) ? sinf(a) : cosf(a));
    }
}

// ------- merged weight transposes: z = which*4 + li; z==28 -> Wenc -----------
__global__ __launch_bounds__(256) void transpose_all_kernel(
    const float* __restrict__ Wq, const float* __restrict__ Wk,
    const float* __restrict__ Wv, const float* __restrict__ Wr,
    const float* __restrict__ Wo, const float* __restrict__ W1,
    const float* __restrict__ W2, const float* __restrict__ Wenc,
    bf16* __restrict__ WqT, bf16* __restrict__ WkvT, bf16* __restrict__ WrT,
    bf16* __restrict__ WoT, bf16* __restrict__ W1T, bf16* __restrict__ W2T,
    bf16* __restrict__ WencT)
{
    __shared__ float t[32][33];
    const int z = blockIdx.z;
    const int bn = blockIdx.x * 32, bk = blockIdx.y * 32;
    const int tx = threadIdx.x & 31, ty = threadIdx.x >> 5;
    if (z == 28) {                         // Wenc: [OBS][E] -> [E][OBS]
        if (blockIdx.y >= OBS / 32) return;
        #pragma unroll
        for (int r = 0; r < 32; r += 8)
            t[ty + r][tx] = Wenc[(size_t)(bk + ty + r) * E + bn + tx];
        __syncthreads();
        #pragma unroll
        for (int r = 0; r < 32; r += 8)
            WencT[(size_t)(bn + ty + r) * OBS + bk + tx] = __float2bfloat16(t[tx][ty + r]);
        return;
    }
    const int which = z >> 2, li = z & 3;
    const size_t so = (size_t)li * E * E;
    const float* src; bf16* dst;
    switch (which) {
        case 0: src = Wq + so; dst = WqT + so; break;
        case 1: src = Wk + so; dst = WkvT + (size_t)li * 2 * E * E; break;
        case 2: src = Wv + so; dst = WkvT + (size_t)li * 2 * E * E + (size_t)E * E; break;
        case 3: src = Wr + so; dst = WrT + so; break;
        case 4: src = Wo + so; dst = WoT + so; break;
        case 5: src = W1 + so; dst = W1T + so; break;
        default: src = W2 + so; dst = W2T + so; break;
    }
    #pragma unroll
    for (int r = 0; r < 32; r += 8)
        t[ty + r][tx] = src[(size_t)(bk + ty + r) * E + bn + tx];
    __syncthreads();
    #pragma unroll
    for (int r = 0; r < 32; r += 8)
        dst[(size_t)(bn + ty + r) * E + bk + tx] = __float2bfloat16(t[tx][ty + r]);
}

// ---------------- V transpose: Vn[B*KLEN][E] bf16 -> Vt[B][E][KLEN'] bf16 ----
// k-axis is sigma-permuted within each 64-block: k' = 4*(k&15) + (k>>4)&3,
// so that flash's softmax can write P with one b64 per row (P/V permuted
// identically => P.V product unchanged). Global writes stay dwordx4-coalesced.
__global__ __launch_bounds__(256) void transpose_v_kernel(
    const bf16* __restrict__ Vn, bf16* __restrict__ Vt)
{
    __shared__ short ts[64][72];
    const int k0 = blockIdx.x * 64, d0 = blockIdx.y * 64, b = blockIdx.z;
    const int t = threadIdx.x;
    const int r = t >> 2, c = (t & 3) * 16;
    const short* src = (const short*)Vn + ((size_t)(b * KLEN + k0 + r)) * E + d0 + c;
    *(uint4*)&ts[r][c]     = *(const uint4*)(src);
    *(uint4*)&ts[r][c + 8] = *(const uint4*)(src + 8);
    __syncthreads();
    short vals[16];
    #pragma unroll
    for (int i = 0; i < 16; ++i) {
        const int kp = c + i;                       // k' within 64
        const int ks = ((kp & 3) << 4) | (kp >> 2); // original k = sigma^-1(k')
        vals[i] = ts[ks][r];
    }
    short* dst = (short*)Vt + ((size_t)(b * E + d0 + r)) * KLEN + k0 + c;
    *(uint4*)(dst)     = *(const uint4*)&vals[0];
    *(uint4*)(dst + 8) = *(const uint4*)&vals[8];
}

// ---------------- 64x64-tile GEMM body: 4 waves of 32x32, BK=64 --------------
// Proven depth-1 reg-staged schedule (R5 win): next K-step's global loads are
// issued between the LDS writes and the raw pre-compute barrier, latency hides
// under MFMA. 18KB LDS -> high blocks/CU for these small-K latency-bound GEMMs.
// Full mode support: 0 = plain (Cf/Cb), 1 = dual-bias Q (QU/QV, pre-scaled /8),
// 2 = KV split (n<512 -> Cb=K, else Cb2=V).
__device__ __forceinline__ void gemm64_body(
    short* As, short* Bs,
    const bf16* __restrict__ A, const bf16* __restrict__ Bt,
    int m0, int n0, int K, int N,
    const float* bias, const float* bias_u, const float* bias_v,
    const float* res, float* Cf, bf16* Cb, bf16* Cb2, int act, int mode)
{
    const int tid = threadIdx.x;
    const int w = tid >> 6, lane = tid & 63;
    const int wm2 = (w >> 1) * 32, wn2 = (w & 1) * 32;
    const int fr = lane & 15, quad = lane >> 4;

    const int arow = tid >> 2, acol = (tid & 3) * 16;  // 64 rows x 64 k
    const short* Ag = (const short*)A + (size_t)(m0 + arow) * K + acol;
    const short* Bg = (const short*)Bt + (size_t)(n0 + arow) * K + acol;
    short* Asw = &As[arow * 72 + acol];
    short* Bsw = &Bs[arow * 72 + acol];

    frag_cd acc[2][2];
    #pragma unroll
    for (int i = 0; i < 2; ++i)
        #pragma unroll
        for (int j = 0; j < 2; ++j)
            acc[i][j] = (frag_cd)(0.0f);

    // prologue: stage regs for k0 = 0
    uint4 a0 = *(const uint4*)(Ag);
    uint4 a1 = *(const uint4*)(Ag + 8);
    uint4 b0 = *(const uint4*)(Bg);
    uint4 b1 = *(const uint4*)(Bg + 8);

    for (int k0 = 0; k0 < K; k0 += 64) {
        __syncthreads();                       // readers of previous tile done
        *(uint4*)(Asw) = a0; *(uint4*)(Asw + 8) = a1;
        *(uint4*)(Bsw) = b0; *(uint4*)(Bsw + 8) = b1;
        if (k0 + 64 < K) {                     // prefetch next tile -> regs
            a0 = *(const uint4*)(Ag + k0 + 64);
            a1 = *(const uint4*)(Ag + k0 + 72);
            b0 = *(const uint4*)(Bg + k0 + 64);
            b1 = *(const uint4*)(Bg + k0 + 72);
        }
        asm volatile("s_waitcnt lgkmcnt(0)" ::: "memory");  // LDS writes visible
        __builtin_amdgcn_s_barrier();                       // no vmcnt drain
        __builtin_amdgcn_sched_barrier(0);
        #pragma unroll
        for (int kh = 0; kh < 2; ++kh) {
            frag_ab af[2], bfr[2];
            #pragma unroll
            for (int i = 0; i < 2; ++i)
                af[i] = *(const frag_ab*)&As[(wm2 + i * 16 + fr) * 72 + kh * 32 + quad * 8];
            #pragma unroll
            for (int j = 0; j < 2; ++j)
                bfr[j] = *(const frag_ab*)&Bs[(wn2 + j * 16 + fr) * 72 + kh * 32 + quad * 8];
            #pragma unroll
            for (int i = 0; i < 2; ++i)
                #pragma unroll
                for (int j = 0; j < 2; ++j)
                    acc[i][j] = __builtin_amdgcn_mfma_f32_16x16x32_bf16(af[i], bfr[j], acc[i][j], 0, 0, 0);
        }
    }

    #pragma unroll
    for (int i = 0; i < 2; ++i) {
        #pragma unroll
        for (int r = 0; r < 4; ++r) {
            const int m = m0 + wm2 + i * 16 + quad * 4 + r;
            #pragma unroll
            for (int j = 0; j < 2; ++j) {
                const int n = n0 + wn2 + j * 16 + fr;
                float v = acc[i][j][r];
                if (bias) v += bias[n];
                if (act)  v = gelu_tanh(v);
                if (res)  v += res[(size_t)m * N + n];
                if (mode == 2) {
                    if (n < 512) Cb[(size_t)m * 512 + n] = __float2bfloat16(v + bias_u[n]);
                    else Cb2[(size_t)m * 512 + (n - 512)] = __float2bfloat16(v + bias_v[n - 512]);
                } else if (mode == 1) {
                    // fold the attention 1/8 scale into QU/QV (exact in bf16)
                    Cb[(size_t)m * N + n]  = __float2bfloat16((v + bias_u[n]) * 0.125f);
                    Cb2[(size_t)m * N + n] = __float2bfloat16((v + bias_v[n]) * 0.125f);
                } else {
                    if (Cf) Cf[(size_t)m * N + n] = v;
                    if (Cb) Cb[(size_t)m * N + n] = __float2bfloat16(v);
                }
            }
        }
    }
}

// ---------------- standalone GEMM (encoder / Wo / W1 / W2) -------------------
// 512 blocks (M=4096/64 x N=512/64), XCD swizzle cpx=64: each XCD keeps 8
// consecutive 64-row A-panels resident in its private L2.
__global__ __launch_bounds__(256) void mfma_gemm_kernel(
    const bf16* __restrict__ A, const bf16* __restrict__ Bt,
    const float* __restrict__ bias, const float* __restrict__ res,
    float* __restrict__ Cf, bf16* __restrict__ Cb,
    int K, int N, int act)
{
    __shared__ short As[64 * 72];
    __shared__ short Bs[64 * 72];
    const int pid = blockIdx.x;                       // 0..511
    const int swz = ((pid & 7) << 6) | (pid >> 3);    // cpx = 64
    gemm64_body(As, Bs, A, Bt, (swz >> 3) * 64, (swz & 7) * 64, K, N,
                bias, nullptr, nullptr, res, Cf, Cb, nullptr, act, 0);
}

// ---------------- fused Q + KV + R projection (one dispatch) -----------------
// 64x64 tiles throughout (R5-proven body). blocks 0..511: Q (M=4096,N=512,
// mode 1 -> QU,QV pre-scaled /8); 512..2559: KV (M=8192,N=1024, mode 2 ->
// KB,VB); 2560..2687: R (M=1024,N=512, mode 0 -> RB). Each range starts at a
// multiple of 8 -> per-range bijective XCD swizzle stays valid.
__global__ __launch_bounds__(256) void qkvr_kernel(
    const bf16* __restrict__ QN, const bf16* __restrict__ VK,
    const bf16* __restrict__ PE_, const bf16* __restrict__ WqT,
    const bf16* __restrict__ WkvT, const bf16* __restrict__ WrT,
    const float* __restrict__ bq, const float* __restrict__ ub,
    const float* __restrict__ vbias, const float* __restrict__ bk,
    const float* __restrict__ bv,
    bf16* __restrict__ QU, bf16* __restrict__ QV,
    bf16* __restrict__ KB, bf16* __restrict__ VB, bf16* __restrict__ RB)
{
    __shared__ short As[64 * 72];
    __shared__ short Bs[64 * 72];
    const int bid = blockIdx.x;
    if (bid < 512) {
        const int swz = ((bid & 7) << 6) | (bid >> 3);         // cpx = 64
        gemm64_body(As, Bs, QN, WqT, (swz >> 3) * 64, (swz & 7) * 64, E, E,
                    bq, ub, vbias, nullptr, nullptr, QU, QV, 0, 1);
    } else if (bid < 2560) {
        const int id = bid - 512;                              // 0..2047
        const int swz = ((id & 7) << 8) | (id >> 3);           // cpx = 256
        gemm64_body(As, Bs, VK, WkvT, (swz >> 4) * 64, (swz & 15) * 64, E, 2 * E,
                    nullptr, bk, bv, nullptr, nullptr, KB, VB, 0, 2);
    } else {
        const int id = bid - 2560;                             // 0..127
        const int swz = ((id & 7) << 4) | (id >> 3);           // cpx = 16
        gemm64_body(As, Bs, PE_, WrT, (swz >> 3) * 64, (swz & 7) * 64, E, E,
                    nullptr, nullptr, nullptr, nullptr, nullptr, RB, nullptr, 0, 0);
    }
}

// ---------------- merged LN pass 1 (memories + x) ----------------------------
__global__ __launch_bounds__(256) void ln1_kernel(
    const float* __restrict__ mem, const float* __restrict__ X, int li,
    const float* __restrict__ gam, const float* __restrict__ bet,
    bf16* __restrict__ qn, bf16* __restrict__ vkdst)
{
    const int blk = blockIdx.x;
    const int t = threadIdx.x;
    const bool isMem = blk < B * MEM;
    const int rr = isMem ? blk : (blk - B * MEM);
    const float* sp = isMem ? (mem + ((size_t)rr * L + li) * E)
                            : (X + (size_t)rr * E);
    const float x0 = sp[t], x1 = sp[t + 256];
    float s = x0 + x1, ss = fmaf(x0, x0, x1 * x1);
    #pragma unroll
    for (int off = 32; off; off >>= 1) { s += __shfl_down(s, off, 64); ss += __shfl_down(ss, off, 64); }
    __shared__ float tmp[8];
    const int wid = t >> 6, lane = t & 63;
    if (!lane) { tmp[wid] = s; tmp[4 + wid] = ss; }
    __syncthreads();
    s = tmp[0] + tmp[1] + tmp[2] + tmp[3];
    ss = tmp[4] + tmp[5] + tmp[6] + tmp[7];
    const float mean = s * (1.0f / E);
    const float var = ss * (1.0f / E) - mean * mean;
    const float rstd = rsqrtf(var + 1e-6f);
    const float y0 = (x0 - mean) * rstd * gam[t] + bet[t];
    const float y1 = (x1 - mean) * rstd * gam[t + 256] + bet[t + 256];
    const int b = rr >> 9, p = rr & 511;
    if (isMem) {
        bf16* dst = vkdst + ((size_t)b * KLEN + p) * E;
        dst[t] = __float2bfloat16(y0); dst[t + 256] = __float2bfloat16(y1);
    } else {
        qn[(size_t)rr * E + t]       = __float2bfloat16(y0);
        qn[(size_t)rr * E + t + 256] = __float2bfloat16(y1);
        bf16* d2 = vkdst + ((size_t)b * KLEN + MEM + p) * E;
        d2[t] = __float2bfloat16(y0); d2[t + 256] = __float2bfloat16(y1);
    }
}

// ---------------- LN (fp32 src -> bf16 dst), used for ln2 --------------------
__global__ __launch_bounds__(256) void ln_f32_kernel(
    const float* __restrict__ src,
    const float* __restrict__ gam, const float* __restrict__ bet,
    bf16* __restrict__ dst1)
{
    const int rr = blockIdx.x;
    const int t = threadIdx.x;
    const float* sp = src + (size_t)rr * E;
    const float x0 = sp[t], x1 = sp[t + 256];
    float s = x0 + x1, ss = fmaf(x0, x0, x1 * x1);
    #pragma unroll
    for (int off = 32; off; off >>= 1) { s += __shfl_down(s, off, 64); ss += __shfl_down(ss, off, 64); }
    __shared__ float tmp[8];
    const int wid = t >> 6, lane = t & 63;
    if (!lane) { tmp[wid] = s; tmp[4 + wid] = ss; }
    __syncthreads();
    s = tmp[0] + tmp[1] + tmp[2] + tmp[3];
    ss = tmp[4] + tmp[5] + tmp[6] + tmp[7];
    const float mean = s * (1.0f / E);
    const float var = ss * (1.0f / E) - mean * mean;
    const float rstd = rsqrtf(var + 1e-6f);
    dst1[(size_t)rr * E + t]       = __float2bfloat16((x0 - mean) * rstd * gam[t] + bet[t]);
    dst1[(size_t)rr * E + t + 256] = __float2bfloat16((x1 - mean) * rstd * gam[t + 256] + bet[t + 256]);
}

// ---------------- MFMA flash attention (swizzled LDS, defer-max) -------------
__global__ __launch_bounds__(256) void mfma_flash_kernel(
    const bf16* __restrict__ Qu,   // [B*S][E]  (pre-scaled by 1/8)
    const bf16* __restrict__ Qv,   // [B*S][E]  (pre-scaled by 1/8)
    const bf16* __restrict__ Kb,   // [B*KLEN][E]
    const bf16* __restrict__ Vt,   // [B][E][KLEN] (k' sigma-permuted per 64)
    const bf16* __restrict__ Rb,   // [KLEN][E]
    bf16* __restrict__ O)          // [B*S][E]
{
    const int pid = blockIdx.x;                       // 0..511
    const int swz = ((pid & 7) << 6) | (pid >> 3);    // cpx = 64; XCD x -> b = x
    const int qphys = swz & 7;
    const int hb = swz >> 3;
    const int h = hb & 7, b = hb >> 3;
    const int qt = (qphys & 1) ? (7 - (qphys >> 1)) : (qphys >> 1);
    const int q0 = qt * FQ;
    const int t = threadIdx.x;
    const int w = t >> 6, lane = t & 63;
    const int fr = lane & 15, quad = lane >> 4;
    const int qbase = q0 + w * 16;

    __shared__ short Ks[64 * 64];      // [k][e], swizzled
    __shared__ short Vs[64 * 64];      // [d][k'], swizzled
    __shared__ short Rs[128 * 64];     // circular R band, swizzled
    __shared__ short BDs[4 * 80 * 18]; // per-wave BD transposed [jlr][qw]
    __shared__ short Ps[4 * 16 * 64];  // per-wave P [q][k'], swizzled

    const int fxk = fr & 7;
    const int xq0 = (quad ^ fxk) << 3;          // cols 0..31  (chunk quad)
    const int xq1 = ((quad + 4) ^ fxk) << 3;    // cols 32..63 (chunk quad+4)

    // Q A-frags straight from global (one-time)
    const short* quptr = (const short*)Qu + ((size_t)(b * S + qbase + fr)) * E + h * DH + quad * 8;
    const frag_ab au0 = *(const frag_ab*)(quptr);
    const frag_ab au1 = *(const frag_ab*)(quptr + 32);
    const short* qvptr = (const short*)Qv + ((size_t)(b * S + qbase + fr)) * E + h * DH + quad * 8;
    const frag_ab av0 = *(const frag_ab*)(qvptr);
    const frag_ab av1 = *(const frag_ab*)(qvptr + 32);

    frag_cd accO[4];
    #pragma unroll
    for (int i = 0; i < 4; ++i) accO[i] = (frag_cd)(0.0f);
    float mrow[4] = {-3.0e38f, -3.0e38f, -3.0e38f, -3.0e38f};
    float lrow[4] = {0.f, 0.f, 0.f, 0.f};   // per-lane partial sums

    const int srow = t >> 2, scol = (t & 3) * 16;   // K/V staging
    const short* kg = (const short*)Kb + ((size_t)(b * KLEN + srow)) * E + h * DH + scol;
    const short* vg = (const short*)Vt + ((size_t)(b * E + h * DH + srow)) * KLEN + scol;
    const int sxs = srow & 7;
    const int scb = (t & 3) * 2;
    const int kvw0 = (srow << 6) + (((scb    ) ^ sxs) << 3);
    const int kvw1 = (srow << 6) + (((scb + 1) ^ sxs) << 3);
    const int ntb0 = 3 - w;            // wave BD window: n-tiles ntb0..ntb0+4
    const int b0 = 448 - q0;           // R band origin at kt=0 (0..448, mult of 64)

    // ---- initial R window: rows j = b0 .. b0+127 (always <= 575, no clamp) --
    {
        const int rr = t >> 1, rc = (t & 1) * 32;
        const int j = b0 + rr;
        const int slot = j & 127;
        const int sx = slot & 7, cb = rc >> 3;
        const short* rp = (const short*)Rb + (size_t)j * E + h * DH + rc;
        *(uint4*)&Rs[(slot << 6) + (((cb    ) ^ sx) << 3)] = *(const uint4*)(rp);
        *(uint4*)&Rs[(slot << 6) + (((cb + 1) ^ sx) << 3)] = *(const uint4*)(rp + 8);
        *(uint4*)&Rs[(slot << 6) + (((cb + 2) ^ sx) << 3)] = *(const uint4*)(rp + 16);
        *(uint4*)&Rs[(slot << 6) + (((cb + 3) ^ sx) << 3)] = *(const uint4*)(rp + 24);
    }

    const int ntiles = 9 + qt;

    // ---- prefetch registers ----
    const int r64 = t >> 2, rc4 = (t & 3) * 16;     // R slide staging
    uint4 ka0, ka1, va0, va1, ra0, ra1;
    int rslot = 0;
    {   // K/V tile 0
        ka0 = *(const uint4*)(kg);
        ka1 = *(const uint4*)(kg + 8);
        va0 = *(const uint4*)(vg);
        va1 = *(const uint4*)(vg + 8);
    }

    for (int kt = 0; kt < ntiles; ++kt) {
        const int k0 = kt * FK;
        __syncthreads();               // previous tile's readers done
        {   // stage K[64k][64e] and V^T[64d][64k'] from prefetched regs
            *(uint4*)&Ks[kvw0] = ka0;
            *(uint4*)&Ks[kvw1] = ka1;
            *(uint4*)&Vs[kvw0] = va0;
            *(uint4*)&Vs[kvw1] = va1;
        }
        if (kt >= 1) {   // slide R window: write 64 prefetched rows
            const int sx = rslot & 7;
            *(uint4*)&Rs[(rslot << 6) + (((scb    ) ^ sx) << 3)] = ra0;
            *(uint4*)&Rs[(rslot << 6) + (((scb + 1) ^ sx) << 3)] = ra1;
        }
        if (kt + 1 < ntiles) {         // prefetch next tile (hides under compute)
            const short* kp = kg + (size_t)(k0 + FK) * E;
            ka0 = *(const uint4*)(kp);
            ka1 = *(const uint4*)(kp + 8);
            const short* vp = vg + k0 + FK;
            va0 = *(const uint4*)(vp);
            va1 = *(const uint4*)(vp + 8);
            int j = b0 + 64 * (kt + 1) + 64 + r64;
            rslot = j & 127;
            if (j > KLEN - 1) j = KLEN - 1;   // clamped rows feed masked scores only
            const short* rp = (const short*)Rb + (size_t)j * E + h * DH + rc4;
            ra0 = *(const uint4*)(rp);
            ra1 = *(const uint4*)(rp + 8);
        }
        asm volatile("s_waitcnt lgkmcnt(0)" ::: "memory");   // LDS writes visible
        __builtin_amdgcn_s_barrier();                        // keep vmcnt in flight
        __builtin_amdgcn_sched_barrier(0);

        const int roff = (b0 + 64 * kt) & 127;   // band start slot (mult of 64)

        // ---- BD tile: BDs[w][jlr][qw] = Qv·R_band^T (wave's 80-col window) --
        __builtin_amdgcn_s_setprio(1);
        #pragma unroll
        for (int i = 0; i < 5; ++i) {
            const int ntb = ntb0 + i;
            const int slot = (roff + ntb * 16 + fr) & 127;   // slot&7 == fr&7
            const frag_ab rf0 = *(const frag_ab*)&Rs[(slot << 6) + xq0];
            const frag_ab rf1 = *(const frag_ab*)&Rs[(slot << 6) + xq1];
            frag_cd z = (frag_cd)(0.0f);
            z = __builtin_amdgcn_mfma_f32_16x16x32_bf16(av0, rf0, z, 0, 0, 0);
            z = __builtin_amdgcn_mfma_f32_16x16x32_bf16(av1, rf1, z, 0, 0, 0);
            union { unsigned u[2]; unsigned short sh[4]; } pk;
            pk.sh[0] = f2bs(z[0]); pk.sh[1] = f2bs(z[1]);
            pk.sh[2] = f2bs(z[2]); pk.sh[3] = f2bs(z[3]);
            const int bdw = (w * 80 + i * 16 + fr) * 18 + quad * 4;
            *(unsigned*)&BDs[bdw]     = pk.u[0];
            *(unsigned*)&BDs[bdw + 2] = pk.u[1];
        }

        // ---- S = Qu·K^T ----
        frag_cd sc[4];
        #pragma unroll
        for (int nt = 0; nt < 4; ++nt) {
            const int krow = (nt * 16 + fr) << 6;
            const frag_ab kf0 = *(const frag_ab*)&Ks[krow + xq0];
            const frag_ab kf1 = *(const frag_ab*)&Ks[krow + xq1];
            frag_cd z = (frag_cd)(0.0f);
            z = __builtin_amdgcn_mfma_f32_16x16x32_bf16(au0, kf0, z, 0, 0, 0);
            z = __builtin_amdgcn_mfma_f32_16x16x32_bf16(au1, kf1, z, 0, 0, 0);
            sc[nt] = z;
        }
        __builtin_amdgcn_s_setprio(0);

        // ---- +BD, mask (last tile only), defer-max online softmax ----
        const bool edge = (kt == ntiles - 1);   // only final tile crosses diagonal
        #pragma unroll
        for (int r = 0; r < 4; ++r) {
            const int qw = quad * 4 + r;
            float sv[4];
            #pragma unroll
            for (int nt = 0; nt < 4; ++nt) {
                const int jlr = nt * 16 + fr + 15 - qw;   // 0..78
                const float bd = bs2f(BDs[(w * 80 + jlr) * 18 + qw]);
                sv[nt] = sc[nt][r] + bd;                  // scale pre-folded into Q
            }
            if (edge) {
                const int qrow = qbase + qw;
                #pragma unroll
                for (int nt = 0; nt < 4; ++nt)
                    if (k0 + nt * 16 + fr > MEM + qrow) sv[nt] = -1e30f;
            }
            const float locmax = fmaxf(fmaxf(sv[0], sv[1]), fmaxf(sv[2], sv[3]));
            if (__any(locmax > mrow[r] + 4.0f)) {   // slow path (rare)
                float tm = locmax;
                tm = fmaxf(tm, __shfl_xor(tm, 1, 64));
                tm = fmaxf(tm, __shfl_xor(tm, 2, 64));
                tm = fmaxf(tm, __shfl_xor(tm, 4, 64));
                tm = fmaxf(tm, __shfl_xor(tm, 8, 64));
                const float mn = fmaxf(mrow[r], tm);
                const float al = __expf(mrow[r] - mn);
                lrow[r] *= al;
                #pragma unroll
                for (int nt = 0; nt < 4; ++nt) accO[nt][r] *= al;
                mrow[r] = mn;
            }
            const float p0 = __expf(sv[0] - mrow[r]), p1 = __expf(sv[1] - mrow[r]);
            const float p2 = __expf(sv[2] - mrow[r]), p3 = __expf(sv[3] - mrow[r]);
            lrow[r] += (p0 + p1) + (p2 + p3);       // per-lane partial
            union { uint2 u2; unsigned short sh[4]; } pq;
            pq.sh[0] = f2bs(p0); pq.sh[1] = f2bs(p1);
            pq.sh[2] = f2bs(p2); pq.sh[3] = f2bs(p3);
            // P[qw][k' = fr*4 .. fr*4+3] -> one aligned b64, swizzled chunk
            const int pw = (w << 10) + (qw << 6)
                         + (((fr >> 1) ^ (qw & 7)) << 3) + ((fr & 1) << 2);
            *(uint2*)&Ps[pw] = pq.u2;
        }

        // ---- O += P·V (per-wave P; same-wave LDS, DS in-order) ----
        const frag_ab pf0 = *(const frag_ab*)&Ps[(w << 10) + (fr << 6) + xq0];
        const frag_ab pf1 = *(const frag_ab*)&Ps[(w << 10) + (fr << 6) + xq1];
        __builtin_amdgcn_s_setprio(1);
        #pragma unroll
        for (int nt = 0; nt < 4; ++nt) {
            const int vrow = (nt * 16 + fr) << 6;
            const frag_ab vf0 = *(const frag_ab*)&Vs[vrow + xq0];
            const frag_ab vf1 = *(const frag_ab*)&Vs[vrow + xq1];
            accO[nt] = __builtin_amdgcn_mfma_f32_16x16x32_bf16(pf0, vf0, accO[nt], 0, 0, 0);
            accO[nt] = __builtin_amdgcn_mfma_f32_16x16x32_bf16(pf1, vf1, accO[nt], 0, 0, 0);
        }
        __builtin_amdgcn_s_setprio(0);
    }

    #pragma unroll
    for (int r = 0; r < 4; ++r) {
        float lsum = lrow[r];                    // reduce once, after the k-loop
        lsum += __shfl_xor(lsum, 1, 64);
        lsum += __shfl_xor(lsum, 2, 64);
        lsum += __shfl_xor(lsum, 4, 64);
        lsum += __shfl_xor(lsum, 8, 64);
        const float inv = 1.0f / lsum;
        bf16* po = O + ((size_t)(b * S + qbase + quad * 4 + r)) * E + h * DH + fr;
        #pragma unroll
        for (int nt = 0; nt < 4; ++nt)
            po[nt * 16] = __float2bfloat16(accO[nt][r] * inv);
    }
}

extern "C" void kernel_launch(void* const* d_in, const int* in_sizes, int n_in,
                              void* d_out, int out_size, void* d_ws, size_t ws_size,
                              hipStream_t stream)
{
    const float* obs  = (const float*)d_in[0];
    const float* mem  = (const float*)d_in[1];
    // d_in[2] = mask: deterministic (k <= MEM + q), recomputed in-kernel
    const float* Wenc = (const float*)d_in[3];
    const float* benc = (const float*)d_in[4];
    const float* ln1s = (const float*)d_in[5];
    const float* ln1b = (const float*)d_in[6];
    const float* Wq   = (const float*)d_in[7];
    const float* bq   = (const float*)d_in[8];
    const float* Wk   = (const float*)d_in[9];
    const float* bk   = (const float*)d_in[10];
    const float* Wv   = (const float*)d_in[11];
    const float* bv   = (const float*)d_in[12];
    const float* Wr   = (const float*)d_in[13];
    const float* ub   = (const float*)d_in[14];
    const float* vb   = (const float*)d_in[15];
    const float* Wo   = (const float*)d_in[16];
    const float* bo   = (const float*)d_in[17];
    const float* ln2s = (const float*)d_in[18];
    const float* ln2b = (const float*)d_in[19];
    const float* W1   = (const float*)d_in[20];
    const float* b1   = (const float*)d_in[21];
    const float* W2   = (const float*)d_in[22];
    const float* b2   = (const float*)d_in[23];

    // ---- workspace ----
    float* wsf = (float*)d_ws;
    float* X = wsf;                                   // fp32 [B*S*E]
    bf16* wsb = (bf16*)(wsf + (size_t)B * S * E);
    size_t ob = 0;
    bf16* OBSb = wsb + ob; ob += (size_t)B * S * OBS;
    bf16* QNb  = wsb + ob; ob += (size_t)B * S * E;
    bf16* PEb  = wsb + ob; ob += (size_t)KLEN * E;
    bf16* RBb  = wsb + ob; ob += (size_t)KLEN * E;
    bf16* WencT= wsb + ob; ob += (size_t)OBS * E;
    bf16* WqT  = wsb + ob; ob += (size_t)L * E * E;
    bf16* WkvT = wsb + ob; ob += (size_t)L * 2 * E * E;   // [L][1024][512]
    bf16* WrT  = wsb + ob; ob += (size_t)L * E * E;
    bf16* WoT  = wsb + ob; ob += (size_t)L * E * E;
    bf16* W1T  = wsb + ob; ob += (size_t)L * E * E;
    bf16* W2T  = wsb + ob; ob += (size_t)L * E * E;
    bf16* QUb  = wsb + ob; ob += (size_t)B * S * E;
    bf16* QVb  = wsb + ob; ob += (size_t)B * S * E;
    bf16* KBb  = wsb + ob; ob += (size_t)B * KLEN * E;
    bf16* VTb  = wsb + ob; ob += (size_t)B * E * KLEN;
    bf16* OBb  = wsb + ob; ob += (size_t)B * S * E;
    // union: {VKb, VBb} ∪ {HB, FFb} (disjoint lifetimes per layer)
    char* uni = (char*)(wsb + ob);
    bf16*  VKb = (bf16*)uni;                          // [B*KLEN][E] (8 MB) @0
    bf16*  VBb = (bf16*)(uni + ((size_t)8 << 20));    // [B*KLEN][E] (8 MB) @8M
    float* HB  = (float*)uni;                         // [B*S][E] fp32 (8 MB) @0
    bf16*  FFb = (bf16*)(uni + ((size_t)8 << 20));    // [B*S][E] (4 MB) @8M

    // ---- setup: merged weight transposes, obs cast + pe ----
    transpose_all_kernel<<<dim3(E / 32, E / 32, 29), 256, 0, stream>>>(
        Wq, Wk, Wv, Wr, Wo, W1, W2, Wenc, WqT, WkvT, WrT, WoT, W1T, W2T, WencT);
    setup_kernel<<<(B * S * OBS + KLEN * E) / 256, 256, 0, stream>>>(obs, OBSb, PEb);

    // encoder: X = obs @ W_enc + b_enc (fp32)
    mfma_gemm_kernel<<<512, 256, 0, stream>>>(
        OBSb, WencT, benc, nullptr, X, nullptr, OBS, E, 0);

    for (int li = 0; li < L; ++li) {
        const size_t wOff = (size_t)li * E * E;
        const size_t vOff = (size_t)li * E;

        ln1_kernel<<<2 * B * S, 256, 0, stream>>>(
            mem, X, li, ln1s + vOff, ln1b + vOff, QNb, VKb);

        qkvr_kernel<<<2688, 256, 0, stream>>>(
            QNb, VKb, PEb, WqT + wOff, WkvT + (size_t)li * 2 * E * E, WrT + wOff,
            bq + vOff, ub + vOff, vb + vOff, bk + vOff, bv + vOff,
            QUb, QVb, KBb, VBb, RBb);

        transpose_v_kernel<<<dim3(KLEN / 64, E / 64, B), 256, 0, stream>>>(VBb, VTb);

        mfma_flash_kernel<<<512, 256, 0, stream>>>(
            QUb, QVb, KBb, VTb, RBb, OBb);

        // HB = X + (O @ Wo + bo)
        mfma_gemm_kernel<<<512, 256, 0, stream>>>(
            OBb, WoT + wOff, bo + vOff, X, HB, nullptr, E, E, 0);
        ln_f32_kernel<<<B * S, 256, 0, stream>>>(HB, ln2s + vOff, ln2b + vOff, QNb);
        // FFb = gelu(hn @ W1 + b1)
        mfma_gemm_kernel<<<512, 256, 0, stream>>>(
            QNb, W1T + wOff, b1 + vOff, nullptr, nullptr, FFb, E, E, 1);
        // X = FF @ W2 + b2 + HB   (last layer writes d_out directly)
        float* dst = (li == L - 1) ? (float*)d_out : X;
        mfma_gemm_kernel<<<512, 256, 0, stream>>>(
            FFb, W2T + wOff, b2 + vOff, HB, dst, nullptr, E, E, 0);
    }
}

// Round 7
// 614.780 us; speedup vs baseline: 1.0302x; 1.0302x over previous
//
#include <hip/hip_runtime.h>
#include <hip/hip_bf16.h>
#include <math.h>

#define B     8
#define S     512
#define MEM   512
#define L     4
#define E     512
#define H     8
#define DH    64
#define OBS   128
#define KLEN  1024   // MEM + S
#define FQ    64     // flash: q rows per block
#define FK    64     // flash: k per tile

typedef __hip_bfloat16 bf16;
using frag_ab = __attribute__((ext_vector_type(8))) short;   // 8 bf16 (4 VGPRs)
using frag_cd = __attribute__((ext_vector_type(4))) float;   // 4 fp32 acc

__device__ __forceinline__ float gelu_tanh(float x) {
    return 0.5f * x * (1.0f + tanhf(0.7978845608028654f * (x + 0.044715f * x * x * x)));
}
__device__ __forceinline__ unsigned short f2bs(float x) {
    bf16 h = __float2bfloat16(x); return *(unsigned short*)&h;
}
__device__ __forceinline__ float bs2f(short s) {
    union { unsigned u; float f; } t; t.u = ((unsigned)(unsigned short)s) << 16; return t.f;
}

// ---------------- merged setup: obs cast + positional embedding --------------
__global__ __launch_bounds__(256) void setup_kernel(
    const float* __restrict__ obs, bf16* __restrict__ obsb, bf16* __restrict__ pe)
{
    const int i = blockIdx.x * 256 + threadIdx.x;
    if (i < B * S * OBS) {
        obsb[i] = __float2bfloat16(obs[i]);
    } else {
        const int idx = i - B * S * OBS;
        const int p = idx >> 9;
        const int j = idx & 511;
        const float pos = (float)(KLEN - p);
        const int m = (j < 256) ? j : (j - 256);
        const float invf = expf(-(float)(2 * m) * (9.210340371976184f / (float)E));
        const float a = pos * invf;
        pe[idx] = __float2bfloat16((j < 256) ? sinf(a) : cosf(a));
    }
}

// ------- merged weight transposes: z = which*4 + li; z==28 -> Wenc -----------
__global__ __launch_bounds__(256) void transpose_all_kernel(
    const float* __restrict__ Wq, const float* __restrict__ Wk,
    const float* __restrict__ Wv, const float* __restrict__ Wr,
    const float* __restrict__ Wo, const float* __restrict__ W1,
    const float* __restrict__ W2, const float* __restrict__ Wenc,
    bf16* __restrict__ WqT, bf16* __restrict__ WkvT, bf16* __restrict__ WrT,
    bf16* __restrict__ WoT, bf16* __restrict__ W1T, bf16* __restrict__ W2T,
    bf16* __restrict__ WencT)
{
    __shared__ float t[32][33];
    const int z = blockIdx.z;
    const int bn = blockIdx.x * 32, bk = blockIdx.y * 32;
    const int tx = threadIdx.x & 31, ty = threadIdx.x >> 5;
    if (z == 28) {                         // Wenc: [OBS][E] -> [E][OBS]
        if (blockIdx.y >= OBS / 32) return;
        #pragma unroll
        for (int r = 0; r < 32; r += 8)
            t[ty + r][tx] = Wenc[(size_t)(bk + ty + r) * E + bn + tx];
        __syncthreads();
        #pragma unroll
        for (int r = 0; r < 32; r += 8)
            WencT[(size_t)(bn + ty + r) * OBS + bk + tx] = __float2bfloat16(t[tx][ty + r]);
        return;
    }
    const int which = z >> 2, li = z & 3;
    const size_t so = (size_t)li * E * E;
    const float* src; bf16* dst;
    switch (which) {
        case 0: src = Wq + so; dst = WqT + so; break;
        case 1: src = Wk + so; dst = WkvT + (size_t)li * 2 * E * E; break;
        case 2: src = Wv + so; dst = WkvT + (size_t)li * 2 * E * E + (size_t)E * E; break;
        case 3: src = Wr + so; dst = WrT + so; break;
        case 4: src = Wo + so; dst = WoT + so; break;
        case 5: src = W1 + so; dst = W1T + so; break;
        default: src = W2 + so; dst = W2T + so; break;
    }
    #pragma unroll
    for (int r = 0; r < 32; r += 8)
        t[ty + r][tx] = src[(size_t)(bk + ty + r) * E + bn + tx];
    __syncthreads();
    #pragma unroll
    for (int r = 0; r < 32; r += 8)
        dst[(size_t)(bn + ty + r) * E + bk + tx] = __float2bfloat16(t[tx][ty + r]);
}

// ---------------- GEMM tile body: 128m x 64n, BK=64, 4 waves of 64x32 --------
// Proven R2/R5 structure: reg-staged depth-1 prefetch; next K-step's global
// loads issue between the LDS writes and the raw pre-compute barrier (latency
// hides under MFMA). Raw s_barrier (lgkmcnt(0) only) avoids hipcc's vmcnt(0)
// drain. Mode 2 with n0>=512 (V-projection blocks) writes the output tile
// TRANSPOSED + sigma-permuted directly to Vt[b][d][k'] via an LDS bounce in
// the (dead) As buffer -- replaces the standalone transpose_v kernel.
__device__ __forceinline__ void gemm_body(
    short* As, short* Bs,
    const bf16* __restrict__ A, const bf16* __restrict__ Bt,
    int m0, int n0, int K, int N,
    const float* bias, const float* bias_u, const float* bias_v,
    const float* res, float* Cf, bf16* Cb, bf16* Cb2, int act, int mode)
{
    const int tid = threadIdx.x;
    const int w = tid >> 6, lane = tid & 63;
    const int wm2 = (w >> 1) * 64, wn2 = (w & 1) * 32;
    const int fr = lane & 15, quad = lane >> 4;

    const int arow = tid >> 1, acol = (tid & 1) * 32;
    const int brow = tid >> 2, bcol = (tid & 3) * 16;
    const short* Ag = (const short*)A + (size_t)(m0 + arow) * K + acol;
    const short* Bg = (const short*)Bt + (size_t)(n0 + brow) * K + bcol;
    short* Asw = &As[arow * 72 + acol];
    short* Bsw = &Bs[brow * 72 + bcol];

    frag_cd acc[4][2];
    #pragma unroll
    for (int i = 0; i < 4; ++i)
        #pragma unroll
        for (int j = 0; j < 2; ++j)
            acc[i][j] = (frag_cd)(0.0f);

    // prologue: stage regs for k0 = 0
    uint4 a0 = *(const uint4*)(Ag);
    uint4 a1 = *(const uint4*)(Ag + 8);
    uint4 a2 = *(const uint4*)(Ag + 16);
    uint4 a3 = *(const uint4*)(Ag + 24);
    uint4 b0 = *(const uint4*)(Bg);
    uint4 b1 = *(const uint4*)(Bg + 8);

    for (int k0 = 0; k0 < K; k0 += 64) {
        __syncthreads();                       // readers of previous tile done
        *(uint4*)(Asw) = a0; *(uint4*)(Asw + 8) = a1;
        *(uint4*)(Asw + 16) = a2; *(uint4*)(Asw + 24) = a3;
        *(uint4*)(Bsw) = b0; *(uint4*)(Bsw + 8) = b1;
        if (k0 + 64 < K) {                     // prefetch next tile -> regs
            a0 = *(const uint4*)(Ag + k0 + 64);
            a1 = *(const uint4*)(Ag + k0 + 72);
            a2 = *(const uint4*)(Ag + k0 + 80);
            a3 = *(const uint4*)(Ag + k0 + 88);
            b0 = *(const uint4*)(Bg + k0 + 64);
            b1 = *(const uint4*)(Bg + k0 + 72);
        }
        asm volatile("s_waitcnt lgkmcnt(0)" ::: "memory");  // LDS writes visible
        __builtin_amdgcn_s_barrier();                       // no vmcnt drain
        __builtin_amdgcn_sched_barrier(0);
        #pragma unroll
        for (int kh = 0; kh < 2; ++kh) {
            frag_ab af[4], bfr[2];
            #pragma unroll
            for (int i = 0; i < 4; ++i)
                af[i] = *(const frag_ab*)&As[(wm2 + i * 16 + fr) * 72 + kh * 32 + quad * 8];
            #pragma unroll
            for (int j = 0; j < 2; ++j)
                bfr[j] = *(const frag_ab*)&Bs[(wn2 + j * 16 + fr) * 72 + kh * 32 + quad * 8];
            #pragma unroll
            for (int i = 0; i < 4; ++i)
                #pragma unroll
                for (int j = 0; j < 2; ++j)
                    acc[i][j] = __builtin_amdgcn_mfma_f32_16x16x32_bf16(af[i], bfr[j], acc[i][j], 0, 0, 0);
        }
    }

    if (mode == 2 && n0 >= 512) {
        // ---- V-projection block: write tile transposed to Vt (=Cb2) ----
        // Tile = 128 k-rows (m) x 64 d-cols (n-512). Stage bf16 into As as
        // ts[d][k] (stride 130 breaks bank alignment), then write sigma-
        // permuted d-rows coalesced: Vt[b][d0+d][kb + k'], k' per 64-block.
        short* ts = As;                        // 64*130 = 8320 <= 128*72 shorts
        __syncthreads();                       // all K-loop LDS readers done
        #pragma unroll
        for (int i = 0; i < 4; ++i) {
            #pragma unroll
            for (int r = 0; r < 4; ++r) {
                const int kl = wm2 + i * 16 + quad * 4 + r;     // 0..127
                #pragma unroll
                for (int j = 0; j < 2; ++j) {
                    const int dl = wn2 + j * 16 + fr;           // 0..63
                    ts[dl * 130 + kl] =
                        (short)f2bs(acc[i][j][r] + bias_v[(n0 - 512) + dl]);
                }
            }
        }
        __syncthreads();
        const int bb = m0 >> 10;               // m0 in [0, 8192)
        const int kb = m0 & 1023;
        const int dl = tid >> 2;               // 0..63
        const int q4 = tid & 3;                // 32 k' each
        short vals[32];
        #pragma unroll
        for (int i2 = 0; i2 < 32; ++i2) {
            const int kp  = q4 * 32 + i2;      // 0..127
            const int kpl = kp & 63;
            const int src = (kp & 64) + (((kpl & 3) << 4) | (kpl >> 2));
            vals[i2] = ts[dl * 130 + src];
        }
        short* dst = (short*)Cb2 + ((size_t)(bb * E + (n0 - 512) + dl)) * KLEN
                   + kb + q4 * 32;
        *(uint4*)(dst)      = *(const uint4*)&vals[0];
        *(uint4*)(dst + 8)  = *(const uint4*)&vals[8];
        *(uint4*)(dst + 16) = *(const uint4*)&vals[16];
        *(uint4*)(dst + 24) = *(const uint4*)&vals[24];
        return;
    }

    #pragma unroll
    for (int i = 0; i < 4; ++i) {
        #pragma unroll
        for (int r = 0; r < 4; ++r) {
            const int m = m0 + wm2 + i * 16 + quad * 4 + r;
            #pragma unroll
            for (int j = 0; j < 2; ++j) {
                const int n = n0 + wn2 + j * 16 + fr;
                float v = acc[i][j][r];
                if (bias) v += bias[n];
                if (act)  v = gelu_tanh(v);
                if (res)  v += res[(size_t)m * N + n];
                if (mode == 2) {                 // K half only (n < 512 here)
                    Cb[(size_t)m * 512 + n] = __float2bfloat16(v + bias_u[n]);
                } else if (mode == 1) {
                    // fold the attention 1/8 scale into QU/QV (exact in bf16)
                    Cb[(size_t)m * N + n]  = __float2bfloat16((v + bias_u[n]) * 0.125f);
                    Cb2[(size_t)m * N + n] = __float2bfloat16((v + bias_v[n]) * 0.125f);
                } else {
                    if (Cf) Cf[(size_t)m * N + n] = v;
                    if (Cb) Cb[(size_t)m * N + n] = __float2bfloat16(v);
                }
            }
        }
    }
}

// ---------------- 64x64-tile GEMM body: 4 waves of 32x32, BK=64 --------------
// R5-proven for the M=4096 standalone GEMMs (2 blocks/CU, 18KB LDS).
__device__ __forceinline__ void gemm64_body(
    short* As, short* Bs,
    const bf16* __restrict__ A, const bf16* __restrict__ Bt,
    int m0, int n0, int K, int N,
    const float* bias, const float* res, float* Cf, bf16* Cb, int act)
{
    const int tid = threadIdx.x;
    const int w = tid >> 6, lane = tid & 63;
    const int wm2 = (w >> 1) * 32, wn2 = (w & 1) * 32;
    const int fr = lane & 15, quad = lane >> 4;

    const int arow = tid >> 2, acol = (tid & 3) * 16;  // 64 rows x 64 k
    const short* Ag = (const short*)A + (size_t)(m0 + arow) * K + acol;
    const short* Bg = (const short*)Bt + (size_t)(n0 + arow) * K + acol;
    short* Asw = &As[arow * 72 + acol];
    short* Bsw = &Bs[arow * 72 + acol];

    frag_cd acc[2][2];
    #pragma unroll
    for (int i = 0; i < 2; ++i)
        #pragma unroll
        for (int j = 0; j < 2; ++j)
            acc[i][j] = (frag_cd)(0.0f);

    // prologue: stage regs for k0 = 0
    uint4 a0 = *(const uint4*)(Ag);
    uint4 a1 = *(const uint4*)(Ag + 8);
    uint4 b0 = *(const uint4*)(Bg);
    uint4 b1 = *(const uint4*)(Bg + 8);

    for (int k0 = 0; k0 < K; k0 += 64) {
        __syncthreads();                       // readers of previous tile done
        *(uint4*)(Asw) = a0; *(uint4*)(Asw + 8) = a1;
        *(uint4*)(Bsw) = b0; *(uint4*)(Bsw + 8) = b1;
        if (k0 + 64 < K) {                     // prefetch next tile -> regs
            a0 = *(const uint4*)(Ag + k0 + 64);
            a1 = *(const uint4*)(Ag + k0 + 72);
            b0 = *(const uint4*)(Bg + k0 + 64);
            b1 = *(const uint4*)(Bg + k0 + 72);
        }
        asm volatile("s_waitcnt lgkmcnt(0)" ::: "memory");  // LDS writes visible
        __builtin_amdgcn_s_barrier();                       // no vmcnt drain
        __builtin_amdgcn_sched_barrier(0);
        #pragma unroll
        for (int kh = 0; kh < 2; ++kh) {
            frag_ab af[2], bfr[2];
            #pragma unroll
            for (int i = 0; i < 2; ++i)
                af[i] = *(const frag_ab*)&As[(wm2 + i * 16 + fr) * 72 + kh * 32 + quad * 8];
            #pragma unroll
            for (int j = 0; j < 2; ++j)
                bfr[j] = *(const frag_ab*)&Bs[(wn2 + j * 16 + fr) * 72 + kh * 32 + quad * 8];
            #pragma unroll
            for (int i = 0; i < 2; ++i)
                #pragma unroll
                for (int j = 0; j < 2; ++j)
                    acc[i][j] = __builtin_amdgcn_mfma_f32_16x16x32_bf16(af[i], bfr[j], acc[i][j], 0, 0, 0);
        }
    }

    #pragma unroll
    for (int i = 0; i < 2; ++i) {
        #pragma unroll
        for (int r = 0; r < 4; ++r) {
            const int m = m0 + wm2 + i * 16 + quad * 4 + r;
            #pragma unroll
            for (int j = 0; j < 2; ++j) {
                const int n = n0 + wn2 + j * 16 + fr;
                float v = acc[i][j][r];
                if (bias) v += bias[n];
                if (act)  v = gelu_tanh(v);
                if (res)  v += res[(size_t)m * N + n];
                if (Cf) Cf[(size_t)m * N + n] = v;
                if (Cb) Cb[(size_t)m * N + n] = __float2bfloat16(v);
            }
        }
    }
}

// ---------------- standalone GEMM (encoder / Wo / W1 / W2) -------------------
// 512 blocks (M=4096/64 x N=512/64), XCD swizzle cpx=64.
__global__ __launch_bounds__(256) void mfma_gemm_kernel(
    const bf16* __restrict__ A, const bf16* __restrict__ Bt,
    const float* __restrict__ bias, const float* __restrict__ res,
    float* __restrict__ Cf, bf16* __restrict__ Cb,
    int K, int N, int act)
{
    __shared__ short As[64 * 72];
    __shared__ short Bs[64 * 72];
    const int pid = blockIdx.x;                       // 0..511
    const int swz = ((pid & 7) << 6) | (pid >> 3);    // cpx = 64
    gemm64_body(As, Bs, A, Bt, (swz >> 3) * 64, (swz & 7) * 64, K, N,
                bias, res, Cf, Cb, act);
}

// ---------------- fused Q + KV + R projection (one dispatch) -----------------
// 128x64 tiles (R5 config). blocks 0..255: Q (mode 1 -> QU,QV /8);
// 256..1279: KV (mode 2; K half -> KB, V half -> transposed Vt directly);
// 1280..1343: R (mode 0 -> RB). Ranges 8-aligned for per-range XCD swizzle.
__global__ __launch_bounds__(256) void qkvr_kernel(
    const bf16* __restrict__ QN, const bf16* __restrict__ VK,
    const bf16* __restrict__ PE_, const bf16* __restrict__ WqT,
    const bf16* __restrict__ WkvT, const bf16* __restrict__ WrT,
    const float* __restrict__ bq, const float* __restrict__ ub,
    const float* __restrict__ vbias, const float* __restrict__ bk,
    const float* __restrict__ bv,
    bf16* __restrict__ QU, bf16* __restrict__ QV,
    bf16* __restrict__ KB, bf16* __restrict__ VT, bf16* __restrict__ RB)
{
    __shared__ short As[128 * 72];
    __shared__ short Bs[64 * 72];
    const int bid = blockIdx.x;
    if (bid < 256) {
        const int swz = ((bid & 7) << 5) | (bid >> 3);        // cpx = 32
        gemm_body(As, Bs, QN, WqT, (swz >> 3) * 128, (swz & 7) * 64, E, E,
                  bq, ub, vbias, nullptr, nullptr, QU, QV, 0, 1);
    } else if (bid < 1280) {
        const int id = bid - 256;                              // 0..1023
        const int swz = ((id & 7) << 7) | (id >> 3);           // cpx = 128
        gemm_body(As, Bs, VK, WkvT, (swz >> 4) * 128, (swz & 15) * 64, E, 2 * E,
                  nullptr, bk, bv, nullptr, nullptr, KB, VT, 0, 2);
    } else {
        const int id = bid - 1280;                             // 0..63
        const int swz = ((id & 7) << 3) | (id >> 3);           // cpx = 8
        gemm_body(As, Bs, PE_, WrT, (swz >> 3) * 128, (swz & 7) * 64, E, E,
                  nullptr, nullptr, nullptr, nullptr, nullptr, RB, nullptr, 0, 0);
    }
}

// ---------------- merged LN pass 1 (memories + x) ----------------------------
__global__ __launch_bounds__(256) void ln1_kernel(
    const float* __restrict__ mem, const float* __restrict__ X, int li,
    const float* __restrict__ gam, const float* __restrict__ bet,
    bf16* __restrict__ qn, bf16* __restrict__ vkdst)
{
    const int blk = blockIdx.x;
    const int t = threadIdx.x;
    const bool isMem = blk < B * MEM;
    const int rr = isMem ? blk : (blk - B * MEM);
    const float* sp = isMem ? (mem + ((size_t)rr * L + li) * E)
                            : (X + (size_t)rr * E);
    const float x0 = sp[t], x1 = sp[t + 256];
    float s = x0 + x1, ss = fmaf(x0, x0, x1 * x1);
    #pragma unroll
    for (int off = 32; off; off >>= 1) { s += __shfl_down(s, off, 64); ss += __shfl_down(ss, off, 64); }
    __shared__ float tmp[8];
    const int wid = t >> 6, lane = t & 63;
    if (!lane) { tmp[wid] = s; tmp[4 + wid] = ss; }
    __syncthreads();
    s = tmp[0] + tmp[1] + tmp[2] + tmp[3];
    ss = tmp[4] + tmp[5] + tmp[6] + tmp[7];
    const float mean = s * (1.0f / E);
    const float var = ss * (1.0f / E) - mean * mean;
    const float rstd = rsqrtf(var + 1e-6f);
    const float y0 = (x0 - mean) * rstd * gam[t] + bet[t];
    const float y1 = (x1 - mean) * rstd * gam[t + 256] + bet[t + 256];
    const int b = rr >> 9, p = rr & 511;
    if (isMem) {
        bf16* dst = vkdst + ((size_t)b * KLEN + p) * E;
        dst[t] = __float2bfloat16(y0); dst[t + 256] = __float2bfloat16(y1);
    } else {
        qn[(size_t)rr * E + t]       = __float2bfloat16(y0);
        qn[(size_t)rr * E + t + 256] = __float2bfloat16(y1);
        bf16* d2 = vkdst + ((size_t)b * KLEN + MEM + p) * E;
        d2[t] = __float2bfloat16(y0); d2[t + 256] = __float2bfloat16(y1);
    }
}

// ---------------- LN (fp32 src -> bf16 dst), used for ln2 --------------------
__global__ __launch_bounds__(256) void ln_f32_kernel(
    const float* __restrict__ src,
    const float* __restrict__ gam, const float* __restrict__ bet,
    bf16* __restrict__ dst1)
{
    const int rr = blockIdx.x;
    const int t = threadIdx.x;
    const float* sp = src + (size_t)rr * E;
    const float x0 = sp[t], x1 = sp[t + 256];
    float s = x0 + x1, ss = fmaf(x0, x0, x1 * x1);
    #pragma unroll
    for (int off = 32; off; off >>= 1) { s += __shfl_down(s, off, 64); ss += __shfl_down(ss, off, 64); }
    __shared__ float tmp[8];
    const int wid = t >> 6, lane = t & 63;
    if (!lane) { tmp[wid] = s; tmp[4 + wid] = ss; }
    __syncthreads();
    s = tmp[0] + tmp[1] + tmp[2] + tmp[3];
    ss = tmp[4] + tmp[5] + tmp[6] + tmp[7];
    const float mean = s * (1.0f / E);
    const float var = ss * (1.0f / E) - mean * mean;
    const float rstd = rsqrtf(var + 1e-6f);
    dst1[(size_t)rr * E + t]       = __float2bfloat16((x0 - mean) * rstd * gam[t] + bet[t]);
    dst1[(size_t)rr * E + t + 256] = __float2bfloat16((x1 - mean) * rstd * gam[t + 256] + bet[t + 256]);
}

// ---------------- MFMA flash attention (swizzled LDS, defer-max) -------------
__global__ __launch_bounds__(256) void mfma_flash_kernel(
    const bf16* __restrict__ Qu,   // [B*S][E]  (pre-scaled by 1/8)
    const bf16* __restrict__ Qv,   // [B*S][E]  (pre-scaled by 1/8)
    const bf16* __restrict__ Kb,   // [B*KLEN][E]
    const bf16* __restrict__ Vt,   // [B][E][KLEN] (k' sigma-permuted per 64)
    const bf16* __restrict__ Rb,   // [KLEN][E]
    bf16* __restrict__ O)          // [B*S][E]
{
    const int pid = blockIdx.x;                       // 0..511
    const int swz = ((pid & 7) << 6) | (pid >> 3);    // cpx = 64; XCD x -> b = x
    const int qphys = swz & 7;
    const int hb = swz >> 3;
    const int h = hb & 7, b = hb >> 3;
    const int qt = (qphys & 1) ? (7 - (qphys >> 1)) : (qphys >> 1);
    const int q0 = qt * FQ;
    const int t = threadIdx.x;
    const int w = t >> 6, lane = t & 63;
    const int fr = lane & 15, quad = lane >> 4;
    const int qbase = q0 + w * 16;

    __shared__ short Ks[64 * 64];      // [k][e], swizzled
    __shared__ short Vs[64 * 64];      // [d][k'], swizzled
    __shared__ short Rs[128 * 64];     // circular R band, swizzled
    __shared__ short BDs[4 * 80 * 18]; // per-wave BD transposed [jlr][qw]
    __shared__ short Ps[4 * 16 * 64];  // per-wave P [q][k'], swizzled

    const int fxk = fr & 7;
    const int xq0 = (quad ^ fxk) << 3;          // cols 0..31  (chunk quad)
    const int xq1 = ((quad + 4) ^ fxk) << 3;    // cols 32..63 (chunk quad+4)

    // Q A-frags straight from global (one-time)
    const short* quptr = (const short*)Qu + ((size_t)(b * S + qbase + fr)) * E + h * DH + quad * 8;
    const frag_ab au0 = *(const frag_ab*)(quptr);
    const frag_ab au1 = *(const frag_ab*)(quptr + 32);
    const short* qvptr = (const short*)Qv + ((size_t)(b * S + qbase + fr)) * E + h * DH + quad * 8;
    const frag_ab av0 = *(const frag_ab*)(qvptr);
    const frag_ab av1 = *(const frag_ab*)(qvptr + 32);

    frag_cd accO[4];
    #pragma unroll
    for (int i = 0; i < 4; ++i) accO[i] = (frag_cd)(0.0f);
    float mrow[4] = {-3.0e38f, -3.0e38f, -3.0e38f, -3.0e38f};
    float lrow[4] = {0.f, 0.f, 0.f, 0.f};   // per-lane partial sums

    const int srow = t >> 2, scol = (t & 3) * 16;   // K/V staging
    const short* kg = (const short*)Kb + ((size_t)(b * KLEN + srow)) * E + h * DH + scol;
    const short* vg = (const short*)Vt + ((size_t)(b * E + h * DH + srow)) * KLEN + scol;
    const int sxs = srow & 7;
    const int scb = (t & 3) * 2;
    const int kvw0 = (srow << 6) + (((scb    ) ^ sxs) << 3);
    const int kvw1 = (srow << 6) + (((scb + 1) ^ sxs) << 3);
    const int ntb0 = 3 - w;            // wave BD window: n-tiles ntb0..ntb0+4
    const int b0 = 448 - q0;           // R band origin at kt=0 (0..448, mult of 64)

    // ---- initial R window: rows j = b0 .. b0+127 (always <= 575, no clamp) --
    {
        const int rr = t >> 1, rc = (t & 1) * 32;
        const int j = b0 + rr;
        const int slot = j & 127;
        const int sx = slot & 7, cb = rc >> 3;
        const short* rp = (const short*)Rb + (size_t)j * E + h * DH + rc;
        *(uint4*)&Rs[(slot << 6) + (((cb    ) ^ sx) << 3)] = *(const uint4*)(rp);
        *(uint4*)&Rs[(slot << 6) + (((cb + 1) ^ sx) << 3)] = *(const uint4*)(rp + 8);
        *(uint4*)&Rs[(slot << 6) + (((cb + 2) ^ sx) << 3)] = *(const uint4*)(rp + 16);
        *(uint4*)&Rs[(slot << 6) + (((cb + 3) ^ sx) << 3)] = *(const uint4*)(rp + 24);
    }

    const int ntiles = 9 + qt;

    // ---- prefetch registers ----
    const int r64 = t >> 2, rc4 = (t & 3) * 16;     // R slide staging
    uint4 ka0, ka1, va0, va1, ra0, ra1;
    int rslot = 0;
    {   // K/V tile 0
        ka0 = *(const uint4*)(kg);
        ka1 = *(const uint4*)(kg + 8);
        va0 = *(const uint4*)(vg);
        va1 = *(const uint4*)(vg + 8);
    }

    for (int kt = 0; kt < ntiles; ++kt) {
        const int k0 = kt * FK;
        __syncthreads();               // previous tile's readers done
        {   // stage K[64k][64e] and V^T[64d][64k'] from prefetched regs
            *(uint4*)&Ks[kvw0] = ka0;
            *(uint4*)&Ks[kvw1] = ka1;
            *(uint4*)&Vs[kvw0] = va0;
            *(uint4*)&Vs[kvw1] = va1;
        }
        if (kt >= 1) {   // slide R window: write 64 prefetched rows
            const int sx = rslot & 7;
            *(uint4*)&Rs[(rslot << 6) + (((scb    ) ^ sx) << 3)] = ra0;
            *(uint4*)&Rs[(rslot << 6) + (((scb + 1) ^ sx) << 3)] = ra1;
        }
        if (kt + 1 < ntiles) {         // prefetch next tile (hides under compute)
            const short* kp = kg + (size_t)(k0 + FK) * E;
            ka0 = *(const uint4*)(kp);
            ka1 = *(const uint4*)(kp + 8);
            const short* vp = vg + k0 + FK;
            va0 = *(const uint4*)(vp);
            va1 = *(const uint4*)(vp + 8);
            int j = b0 + 64 * (kt + 1) + 64 + r64;
            rslot = j & 127;
            if (j > KLEN - 1) j = KLEN - 1;   // clamped rows feed masked scores only
            const short* rp = (const short*)Rb + (size_t)j * E + h * DH + rc4;
            ra0 = *(const uint4*)(rp);
            ra1 = *(const uint4*)(rp + 8);
        }
        asm volatile("s_waitcnt lgkmcnt(0)" ::: "memory");   // LDS writes visible
        __builtin_amdgcn_s_barrier();                        // keep vmcnt in flight
        __builtin_amdgcn_sched_barrier(0);

        const int roff = (b0 + 64 * kt) & 127;   // band start slot (mult of 64)

        // ---- BD tile: BDs[w][jlr][qw] = Qv·R_band^T (wave's 80-col window) --
        __builtin_amdgcn_s_setprio(1);
        #pragma unroll
        for (int i = 0; i < 5; ++i) {
            const int ntb = ntb0 + i;
            const int slot = (roff + ntb * 16 + fr) & 127;   // slot&7 == fr&7
            const frag_ab rf0 = *(const frag_ab*)&Rs[(slot << 6) + xq0];
            const frag_ab rf1 = *(const frag_ab*)&Rs[(slot << 6) + xq1];
            frag_cd z = (frag_cd)(0.0f);
            z = __builtin_amdgcn_mfma_f32_16x16x32_bf16(av0, rf0, z, 0, 0, 0);
            z = __builtin_amdgcn_mfma_f32_16x16x32_bf16(av1, rf1, z, 0, 0, 0);
            union { unsigned u[2]; unsigned short sh[4]; } pk;
            pk.sh[0] = f2bs(z[0]); pk.sh[1] = f2bs(z[1]);
            pk.sh[2] = f2bs(z[2]); pk.sh[3] = f2bs(z[3]);
            const int bdw = (w * 80 + i * 16 + fr) * 18 + quad * 4;
            *(unsigned*)&BDs[bdw]     = pk.u[0];
            *(unsigned*)&BDs[bdw + 2] = pk.u[1];
        }

        // ---- S = Qu·K^T ----
        frag_cd sc[4];
        #pragma unroll
        for (int nt = 0; nt < 4; ++nt) {
            const int krow = (nt * 16 + fr) << 6;
            const frag_ab kf0 = *(const frag_ab*)&Ks[krow + xq0];
            const frag_ab kf1 = *(const frag_ab*)&Ks[krow + xq1];
            frag_cd z = (frag_cd)(0.0f);
            z = __builtin_amdgcn_mfma_f32_16x16x32_bf16(au0, kf0, z, 0, 0, 0);
            z = __builtin_amdgcn_mfma_f32_16x16x32_bf16(au1, kf1, z, 0, 0, 0);
            sc[nt] = z;
        }
        __builtin_amdgcn_s_setprio(0);

        // ---- +BD, mask (last tile only), defer-max online softmax ----
        const bool edge = (kt == ntiles - 1);   // only final tile crosses diagonal
        #pragma unroll
        for (int r = 0; r < 4; ++r) {
            const int qw = quad * 4 + r;
            float sv[4];
            #pragma unroll
            for (int nt = 0; nt < 4; ++nt) {
                const int jlr = nt * 16 + fr + 15 - qw;   // 0..78
                const float bd = bs2f(BDs[(w * 80 + jlr) * 18 + qw]);
                sv[nt] = sc[nt][r] + bd;                  // scale pre-folded into Q
            }
            if (edge) {
                const int qrow = qbase + qw;
                #pragma unroll
                for (int nt = 0; nt < 4; ++nt)
                    if (k0 + nt * 16 + fr > MEM + qrow) sv[nt] = -1e30f;
            }
            const float locmax = fmaxf(fmaxf(sv[0], sv[1]), fmaxf(sv[2], sv[3]));
            if (__any(locmax > mrow[r] + 4.0f)) {   // slow path (rare)
                float tm = locmax;
                tm = fmaxf(tm, __shfl_xor(tm, 1, 64));
                tm = fmaxf(tm, __shfl_xor(tm, 2, 64));
                tm = fmaxf(tm, __shfl_xor(tm, 4, 64));
                tm = fmaxf(tm, __shfl_xor(tm, 8, 64));
                const float mn = fmaxf(mrow[r], tm);
                const float al = __expf(mrow[r] - mn);
                lrow[r] *= al;
                #pragma unroll
                for (int nt = 0; nt < 4; ++nt) accO[nt][r] *= al;
                mrow[r] = mn;
            }
            const float p0 = __expf(sv[0] - mrow[r]), p1 = __expf(sv[1] - mrow[r]);
            const float p2 = __expf(sv[2] - mrow[r]), p3 = __expf(sv[3] - mrow[r]);
            lrow[r] += (p0 + p1) + (p2 + p3);       // per-lane partial
            union { uint2 u2; unsigned short sh[4]; } pq;
            pq.sh[0] = f2bs(p0); pq.sh[1] = f2bs(p1);
            pq.sh[2] = f2bs(p2); pq.sh[3] = f2bs(p3);
            // P[qw][k' = fr*4 .. fr*4+3] -> one aligned b64, swizzled chunk
            const int pw = (w << 10) + (qw << 6)
                         + (((fr >> 1) ^ (qw & 7)) << 3) + ((fr & 1) << 2);
            *(uint2*)&Ps[pw] = pq.u2;
        }

        // ---- O += P·V (per-wave P; same-wave LDS, DS in-order) ----
        const frag_ab pf0 = *(const frag_ab*)&Ps[(w << 10) + (fr << 6) + xq0];
        const frag_ab pf1 = *(const frag_ab*)&Ps[(w << 10) + (fr << 6) + xq1];
        __builtin_amdgcn_s_setprio(1);
        #pragma unroll
        for (int nt = 0; nt < 4; ++nt) {
            const int vrow = (nt * 16 + fr) << 6;
            const frag_ab vf0 = *(const frag_ab*)&Vs[vrow + xq0];
            const frag_ab vf1 = *(const frag_ab*)&Vs[vrow + xq1];
            accO[nt] = __builtin_amdgcn_mfma_f32_16x16x32_bf16(pf0, vf0, accO[nt], 0, 0, 0);
            accO[nt] = __builtin_amdgcn_mfma_f32_16x16x32_bf16(pf1, vf1, accO[nt], 0, 0, 0);
        }
        __builtin_amdgcn_s_setprio(0);
    }

    #pragma unroll
    for (int r = 0; r < 4; ++r) {
        float lsum = lrow[r];                    // reduce once, after the k-loop
        lsum += __shfl_xor(lsum, 1, 64);
        lsum += __shfl_xor(lsum, 2, 64);
        lsum += __shfl_xor(lsum, 4, 64);
        lsum += __shfl_xor(lsum, 8, 64);
        const float inv = 1.0f / lsum;
        bf16* po = O + ((size_t)(b * S + qbase + quad * 4 + r)) * E + h * DH + fr;
        #pragma unroll
        for (int nt = 0; nt < 4; ++nt)
            po[nt * 16] = __float2bfloat16(accO[nt][r] * inv);
    }
}

extern "C" void kernel_launch(void* const* d_in, const int* in_sizes, int n_in,
                              void* d_out, int out_size, void* d_ws, size_t ws_size,
                              hipStream_t stream)
{
    const float* obs  = (const float*)d_in[0];
    const float* mem  = (const float*)d_in[1];
    // d_in[2] = mask: deterministic (k <= MEM + q), recomputed in-kernel
    const float* Wenc = (const float*)d_in[3];
    const float* benc = (const float*)d_in[4];
    const float* ln1s = (const float*)d_in[5];
    const float* ln1b = (const float*)d_in[6];
    const float* Wq   = (const float*)d_in[7];
    const float* bq   = (const float*)d_in[8];
    const float* Wk   = (const float*)d_in[9];
    const float* bk   = (const float*)d_in[10];
    const float* Wv   = (const float*)d_in[11];
    const float* bv   = (const float*)d_in[12];
    const float* Wr   = (const float*)d_in[13];
    const float* ub   = (const float*)d_in[14];
    const float* vb   = (const float*)d_in[15];
    const float* Wo   = (const float*)d_in[16];
    const float* bo   = (const float*)d_in[17];
    const float* ln2s = (const float*)d_in[18];
    const float* ln2b = (const float*)d_in[19];
    const float* W1   = (const float*)d_in[20];
    const float* b1   = (const float*)d_in[21];
    const float* W2   = (const float*)d_in[22];
    const float* b2   = (const float*)d_in[23];

    // ---- workspace ----
    float* wsf = (float*)d_ws;
    float* X = wsf;                                   // fp32 [B*S*E]
    bf16* wsb = (bf16*)(wsf + (size_t)B * S * E);
    size_t ob = 0;
    bf16* OBSb = wsb + ob; ob += (size_t)B * S * OBS;
    bf16* QNb  = wsb + ob; ob += (size_t)B * S * E;
    bf16* PEb  = wsb + ob; ob += (size_t)KLEN * E;
    bf16* RBb  = wsb + ob; ob += (size_t)KLEN * E;
    bf16* WencT= wsb + ob; ob += (size_t)OBS * E;
    bf16* WqT  = wsb + ob; ob += (size_t)L * E * E;
    bf16* WkvT = wsb + ob; ob += (size_t)L * 2 * E * E;   // [L][1024][512]
    bf16* WrT  = wsb + ob; ob += (size_t)L * E * E;
    bf16* WoT  = wsb + ob; ob += (size_t)L * E * E;
    bf16* W1T  = wsb + ob; ob += (size_t)L * E * E;
    bf16* W2T  = wsb + ob; ob += (size_t)L * E * E;
    bf16* QUb  = wsb + ob; ob += (size_t)B * S * E;
    bf16* QVb  = wsb + ob; ob += (size_t)B * S * E;
    bf16* KBb  = wsb + ob; ob += (size_t)B * KLEN * E;
    bf16* VTb  = wsb + ob; ob += (size_t)B * E * KLEN;
    bf16* OBb  = wsb + ob; ob += (size_t)B * S * E;
    // union: {VKb} ∪ {HB, FFb} (disjoint lifetimes per layer)
    char* uni = (char*)(wsb + ob);
    bf16*  VKb = (bf16*)uni;                          // [B*KLEN][E] (8 MB) @0
    float* HB  = (float*)uni;                         // [B*S][E] fp32 (8 MB) @0
    bf16*  FFb = (bf16*)(uni + ((size_t)8 << 20));    // [B*S][E] (4 MB) @8M

    // NOTE: VKb (qkvr input) and HB (Wo output) share @0 — lifetimes disjoint:
    // VKb live ln1->qkvr; HB live Wo-gemm->W2-gemm. qkvr finishes before Wo runs.

    // ---- setup: merged weight transposes, obs cast + pe ----
    transpose_all_kernel<<<dim3(E / 32, E / 32, 29), 256, 0, stream>>>(
        Wq, Wk, Wv, Wr, Wo, W1, W2, Wenc, WqT, WkvT, WrT, WoT, W1T, W2T, WencT);
    setup_kernel<<<(B * S * OBS + KLEN * E) / 256, 256, 0, stream>>>(obs, OBSb, PEb);

    // encoder: X = obs @ W_enc + b_enc (fp32)
    mfma_gemm_kernel<<<512, 256, 0, stream>>>(
        OBSb, WencT, benc, nullptr, X, nullptr, OBS, E, 0);

    for (int li = 0; li < L; ++li) {
        const size_t wOff = (size_t)li * E * E;
        const size_t vOff = (size_t)li * E;

        ln1_kernel<<<2 * B * S, 256, 0, stream>>>(
            mem, X, li, ln1s + vOff, ln1b + vOff, QNb, VKb);

        // qkvr writes V directly transposed to VTb (no transpose_v kernel)
        qkvr_kernel<<<1344, 256, 0, stream>>>(
            QNb, VKb, PEb, WqT + wOff, WkvT + (size_t)li * 2 * E * E, WrT + wOff,
            bq + vOff, ub + vOff, vb + vOff, bk + vOff, bv + vOff,
            QUb, QVb, KBb, VTb, RBb);

        mfma_flash_kernel<<<512, 256, 0, stream>>>(
            QUb, QVb, KBb, VTb, RBb, OBb);

        // HB = X + (O @ Wo + bo)
        mfma_gemm_kernel<<<512, 256, 0, stream>>>(
            OBb, WoT + wOff, bo + vOff, X, HB, nullptr, E, E, 0);
        ln_f32_kernel<<<B * S, 256, 0, stream>>>(HB, ln2s + vOff, ln2b + vOff, QNb);
        // FFb = gelu(hn @ W1 + b1)
        mfma_gemm_kernel<<<512, 256, 0, stream>>>(
            QNb, W1T + wOff, b1 + vOff, nullptr, nullptr, FFb, E, E, 1);
        // X = FF @ W2 + b2 + HB   (last layer writes d_out directly)
        float* dst = (li == L - 1) ? (float*)d_out : X;
        mfma_gemm_kernel<<<512, 256, 0, stream>>>(
            FFb, W2T + wOff, b2 + vOff, HB, dst, nullptr, E, E, 0);
    }
}

// Round 8
// 580.579 us; speedup vs baseline: 1.0909x; 1.0589x over previous
//
#include <hip/hip_runtime.h>
#include <hip/hip_bf16.h>
#include <math.h>

#define B     8
#define S     512
#define MEM   512
#define L     4
#define E     512
#define H     8
#define DH    64
#define OBS   128
#define KLEN  1024   // MEM + S
#define FQ    64     // flash: q rows per block
#define FK    64     // flash: k per tile

typedef __hip_bfloat16 bf16;
using frag_ab = __attribute__((ext_vector_type(8))) short;   // 8 bf16 (4 VGPRs)
using frag_cd = __attribute__((ext_vector_type(4))) float;   // 4 fp32 acc

__device__ __forceinline__ float gelu_tanh(float x) {
    return 0.5f * x * (1.0f + tanhf(0.7978845608028654f * (x + 0.044715f * x * x * x)));
}
__device__ __forceinline__ unsigned short f2bs(float x) {
    bf16 h = __float2bfloat16(x); return *(unsigned short*)&h;
}
__device__ __forceinline__ float bs2f(short s) {
    union { unsigned u; float f; } t; t.u = ((unsigned)(unsigned short)s) << 16; return t.f;
}

// ---------------- merged setup: obs cast + positional embedding --------------
__global__ __launch_bounds__(256) void setup_kernel(
    const float* __restrict__ obs, bf16* __restrict__ obsb, bf16* __restrict__ pe)
{
    const int i = blockIdx.x * 256 + threadIdx.x;
    if (i < B * S * OBS) {
        obsb[i] = __float2bfloat16(obs[i]);
    } else {
        const int idx = i - B * S * OBS;
        const int p = idx >> 9;
        const int j = idx & 511;
        const float pos = (float)(KLEN - p);
        const int m = (j < 256) ? j : (j - 256);
        const float invf = expf(-(float)(2 * m) * (9.210340371976184f / (float)E));
        const float a = pos * invf;
        pe[idx] = __float2bfloat16((j < 256) ? sinf(a) : cosf(a));
    }
}

// ------- merged weight transposes: z = which*4 + li; z==28 -> Wenc -----------
__global__ __launch_bounds__(256) void transpose_all_kernel(
    const float* __restrict__ Wq, const float* __restrict__ Wk,
    const float* __restrict__ Wv, const float* __restrict__ Wr,
    const float* __restrict__ Wo, const float* __restrict__ W1,
    const float* __restrict__ W2, const float* __restrict__ Wenc,
    bf16* __restrict__ WqT, bf16* __restrict__ WkvT, bf16* __restrict__ WrT,
    bf16* __restrict__ WoT, bf16* __restrict__ W1T, bf16* __restrict__ W2T,
    bf16* __restrict__ WencT)
{
    __shared__ float t[32][33];
    const int z = blockIdx.z;
    const int bn = blockIdx.x * 32, bk = blockIdx.y * 32;
    const int tx = threadIdx.x & 31, ty = threadIdx.x >> 5;
    if (z == 28) {                         // Wenc: [OBS][E] -> [E][OBS]
        if (blockIdx.y >= OBS / 32) return;
        #pragma unroll
        for (int r = 0; r < 32; r += 8)
            t[ty + r][tx] = Wenc[(size_t)(bk + ty + r) * E + bn + tx];
        __syncthreads();
        #pragma unroll
        for (int r = 0; r < 32; r += 8)
            WencT[(size_t)(bn + ty + r) * OBS + bk + tx] = __float2bfloat16(t[tx][ty + r]);
        return;
    }
    const int which = z >> 2, li = z & 3;
    const size_t so = (size_t)li * E * E;
    const float* src; bf16* dst;
    switch (which) {
        case 0: src = Wq + so; dst = WqT + so; break;
        case 1: src = Wk + so; dst = WkvT + (size_t)li * 2 * E * E; break;
        case 2: src = Wv + so; dst = WkvT + (size_t)li * 2 * E * E + (size_t)E * E; break;
        case 3: src = Wr + so; dst = WrT + so; break;
        case 4: src = Wo + so; dst = WoT + so; break;
        case 5: src = W1 + so; dst = W1T + so; break;
        default: src = W2 + so; dst = W2T + so; break;
    }
    #pragma unroll
    for (int r = 0; r < 32; r += 8)
        t[ty + r][tx] = src[(size_t)(bk + ty + r) * E + bn + tx];
    __syncthreads();
    #pragma unroll
    for (int r = 0; r < 32; r += 8)
        dst[(size_t)(bn + ty + r) * E + bk + tx] = __float2bfloat16(t[tx][ty + r]);
}

// ---------------- GEMM tile body: 128m x 64n, BK=64, 4 waves of 64x32 --------
// Proven R2/R5 structure: reg-staged depth-1 prefetch. Mode 2 with n0>=512
// (V-projection blocks) writes the output tile TRANSPOSED + sigma-permuted
// directly to Vt[b][d][k'] via an LDS bounce in the (dead) As buffer.
__device__ __forceinline__ void gemm_body(
    short* As, short* Bs,
    const bf16* __restrict__ A, const bf16* __restrict__ Bt,
    int m0, int n0, int K, int N,
    const float* bias, const float* bias_u, const float* bias_v,
    const float* res, float* Cf, bf16* Cb, bf16* Cb2, int act, int mode)
{
    const int tid = threadIdx.x;
    const int w = tid >> 6, lane = tid & 63;
    const int wm2 = (w >> 1) * 64, wn2 = (w & 1) * 32;
    const int fr = lane & 15, quad = lane >> 4;

    const int arow = tid >> 1, acol = (tid & 1) * 32;
    const int brow = tid >> 2, bcol = (tid & 3) * 16;
    const short* Ag = (const short*)A + (size_t)(m0 + arow) * K + acol;
    const short* Bg = (const short*)Bt + (size_t)(n0 + brow) * K + bcol;
    short* Asw = &As[arow * 72 + acol];
    short* Bsw = &Bs[brow * 72 + bcol];

    frag_cd acc[4][2];
    #pragma unroll
    for (int i = 0; i < 4; ++i)
        #pragma unroll
        for (int j = 0; j < 2; ++j)
            acc[i][j] = (frag_cd)(0.0f);

    // prologue: stage regs for k0 = 0
    uint4 a0 = *(const uint4*)(Ag);
    uint4 a1 = *(const uint4*)(Ag + 8);
    uint4 a2 = *(const uint4*)(Ag + 16);
    uint4 a3 = *(const uint4*)(Ag + 24);
    uint4 b0 = *(const uint4*)(Bg);
    uint4 b1 = *(const uint4*)(Bg + 8);

    for (int k0 = 0; k0 < K; k0 += 64) {
        __syncthreads();                       // readers of previous tile done
        *(uint4*)(Asw) = a0; *(uint4*)(Asw + 8) = a1;
        *(uint4*)(Asw + 16) = a2; *(uint4*)(Asw + 24) = a3;
        *(uint4*)(Bsw) = b0; *(uint4*)(Bsw + 8) = b1;
        if (k0 + 64 < K) {                     // prefetch next tile -> regs
            a0 = *(const uint4*)(Ag + k0 + 64);
            a1 = *(const uint4*)(Ag + k0 + 72);
            a2 = *(const uint4*)(Ag + k0 + 80);
            a3 = *(const uint4*)(Ag + k0 + 88);
            b0 = *(const uint4*)(Bg + k0 + 64);
            b1 = *(const uint4*)(Bg + k0 + 72);
        }
        asm volatile("s_waitcnt lgkmcnt(0)" ::: "memory");  // LDS writes visible
        __builtin_amdgcn_s_barrier();                       // no vmcnt drain
        __builtin_amdgcn_sched_barrier(0);
        #pragma unroll
        for (int kh = 0; kh < 2; ++kh) {
            frag_ab af[4], bfr[2];
            #pragma unroll
            for (int i = 0; i < 4; ++i)
                af[i] = *(const frag_ab*)&As[(wm2 + i * 16 + fr) * 72 + kh * 32 + quad * 8];
            #pragma unroll
            for (int j = 0; j < 2; ++j)
                bfr[j] = *(const frag_ab*)&Bs[(wn2 + j * 16 + fr) * 72 + kh * 32 + quad * 8];
            #pragma unroll
            for (int i = 0; i < 4; ++i)
                #pragma unroll
                for (int j = 0; j < 2; ++j)
                    acc[i][j] = __builtin_amdgcn_mfma_f32_16x16x32_bf16(af[i], bfr[j], acc[i][j], 0, 0, 0);
        }
    }

    if (mode == 2 && n0 >= 512) {
        // ---- V-projection block: write tile transposed to Vt (=Cb2) ----
        short* ts = As;                        // 64*130 = 8320 <= 128*72 shorts
        __syncthreads();                       // all K-loop LDS readers done
        #pragma unroll
        for (int i = 0; i < 4; ++i) {
            #pragma unroll
            for (int r = 0; r < 4; ++r) {
                const int kl = wm2 + i * 16 + quad * 4 + r;     // 0..127
                #pragma unroll
                for (int j = 0; j < 2; ++j) {
                    const int dl = wn2 + j * 16 + fr;           // 0..63
                    ts[dl * 130 + kl] =
                        (short)f2bs(acc[i][j][r] + bias_v[(n0 - 512) + dl]);
                }
            }
        }
        __syncthreads();
        const int bb = m0 >> 10;               // m0 in [0, 8192)
        const int kb = m0 & 1023;
        const int dl = tid >> 2;               // 0..63
        const int q4 = tid & 3;                // 32 k' each
        short vals[32];
        #pragma unroll
        for (int i2 = 0; i2 < 32; ++i2) {
            const int kp  = q4 * 32 + i2;      // 0..127
            const int kpl = kp & 63;
            const int src = (kp & 64) + (((kpl & 3) << 4) | (kpl >> 2));
            vals[i2] = ts[dl * 130 + src];
        }
        short* dst = (short*)Cb2 + ((size_t)(bb * E + (n0 - 512) + dl)) * KLEN
                   + kb + q4 * 32;
        *(uint4*)(dst)      = *(const uint4*)&vals[0];
        *(uint4*)(dst + 8)  = *(const uint4*)&vals[8];
        *(uint4*)(dst + 16) = *(const uint4*)&vals[16];
        *(uint4*)(dst + 24) = *(const uint4*)&vals[24];
        return;
    }

    #pragma unroll
    for (int i = 0; i < 4; ++i) {
        #pragma unroll
        for (int r = 0; r < 4; ++r) {
            const int m = m0 + wm2 + i * 16 + quad * 4 + r;
            #pragma unroll
            for (int j = 0; j < 2; ++j) {
                const int n = n0 + wn2 + j * 16 + fr;
                float v = acc[i][j][r];
                if (bias) v += bias[n];
                if (act)  v = gelu_tanh(v);
                if (res)  v += res[(size_t)m * N + n];
                if (mode == 2) {                 // K half only (n < 512 here)
                    Cb[(size_t)m * 512 + n] = __float2bfloat16(v + bias_u[n]);
                } else if (mode == 1) {
                    // fold the attention 1/8 scale into QU/QV (exact in bf16)
                    Cb[(size_t)m * N + n]  = __float2bfloat16((v + bias_u[n]) * 0.125f);
                    Cb2[(size_t)m * N + n] = __float2bfloat16((v + bias_v[n]) * 0.125f);
                } else {
                    if (Cf) Cf[(size_t)m * N + n] = v;
                    if (Cb) Cb[(size_t)m * N + n] = __float2bfloat16(v);
                }
            }
        }
    }
}

// ---------------- 64x64-tile GEMM body: 4 waves of 32x32, BK=64 --------------
// R5-proven for the M=4096 standalone GEMMs. Optional stats: per-row {sum,
// sumsq} of the final output accumulated via shfl-reduce + atomicAdd (feeds
// the inline-LN of the next GEMM, replacing the standalone ln2 kernel).
__device__ __forceinline__ void gemm64_body(
    short* As, short* Bs,
    const bf16* __restrict__ A, const bf16* __restrict__ Bt,
    int m0, int n0, int K, int N,
    const float* bias, const float* res, float* Cf, bf16* Cb, int act,
    float* stats)
{
    const int tid = threadIdx.x;
    const int w = tid >> 6, lane = tid & 63;
    const int wm2 = (w >> 1) * 32, wn2 = (w & 1) * 32;
    const int fr = lane & 15, quad = lane >> 4;

    const int arow = tid >> 2, acol = (tid & 3) * 16;  // 64 rows x 64 k
    const short* Ag = (const short*)A + (size_t)(m0 + arow) * K + acol;
    const short* Bg = (const short*)Bt + (size_t)(n0 + arow) * K + acol;
    short* Asw = &As[arow * 72 + acol];
    short* Bsw = &Bs[arow * 72 + acol];

    frag_cd acc[2][2];
    #pragma unroll
    for (int i = 0; i < 2; ++i)
        #pragma unroll
        for (int j = 0; j < 2; ++j)
            acc[i][j] = (frag_cd)(0.0f);

    // prologue: stage regs for k0 = 0
    uint4 a0 = *(const uint4*)(Ag);
    uint4 a1 = *(const uint4*)(Ag + 8);
    uint4 b0 = *(const uint4*)(Bg);
    uint4 b1 = *(const uint4*)(Bg + 8);

    for (int k0 = 0; k0 < K; k0 += 64) {
        __syncthreads();                       // readers of previous tile done
        *(uint4*)(Asw) = a0; *(uint4*)(Asw + 8) = a1;
        *(uint4*)(Bsw) = b0; *(uint4*)(Bsw + 8) = b1;
        if (k0 + 64 < K) {                     // prefetch next tile -> regs
            a0 = *(const uint4*)(Ag + k0 + 64);
            a1 = *(const uint4*)(Ag + k0 + 72);
            b0 = *(const uint4*)(Bg + k0 + 64);
            b1 = *(const uint4*)(Bg + k0 + 72);
        }
        asm volatile("s_waitcnt lgkmcnt(0)" ::: "memory");  // LDS writes visible
        __builtin_amdgcn_s_barrier();                       // no vmcnt drain
        __builtin_amdgcn_sched_barrier(0);
        #pragma unroll
        for (int kh = 0; kh < 2; ++kh) {
            frag_ab af[2], bfr[2];
            #pragma unroll
            for (int i = 0; i < 2; ++i)
                af[i] = *(const frag_ab*)&As[(wm2 + i * 16 + fr) * 72 + kh * 32 + quad * 8];
            #pragma unroll
            for (int j = 0; j < 2; ++j)
                bfr[j] = *(const frag_ab*)&Bs[(wn2 + j * 16 + fr) * 72 + kh * 32 + quad * 8];
            #pragma unroll
            for (int i = 0; i < 2; ++i)
                #pragma unroll
                for (int j = 0; j < 2; ++j)
                    acc[i][j] = __builtin_amdgcn_mfma_f32_16x16x32_bf16(af[i], bfr[j], acc[i][j], 0, 0, 0);
        }
    }

    #pragma unroll
    for (int i = 0; i < 2; ++i) {
        #pragma unroll
        for (int r = 0; r < 4; ++r) {
            const int m = m0 + wm2 + i * 16 + quad * 4 + r;
            float s = 0.0f, sq = 0.0f;
            #pragma unroll
            for (int j = 0; j < 2; ++j) {
                const int n = n0 + wn2 + j * 16 + fr;
                float v = acc[i][j][r];
                if (bias) v += bias[n];
                if (act)  v = gelu_tanh(v);
                if (res)  v += res[(size_t)m * N + n];
                if (Cf) Cf[(size_t)m * N + n] = v;
                if (Cb) Cb[(size_t)m * N + n] = __float2bfloat16(v);
                s += v; sq = fmaf(v, v, sq);
            }
            if (stats) {                        // row stats for downstream LN
                s  += __shfl_xor(s, 1, 64);  sq += __shfl_xor(sq, 1, 64);
                s  += __shfl_xor(s, 2, 64);  sq += __shfl_xor(sq, 2, 64);
                s  += __shfl_xor(s, 4, 64);  sq += __shfl_xor(sq, 4, 64);
                s  += __shfl_xor(s, 8, 64);  sq += __shfl_xor(sq, 8, 64);
                if (fr == 0) {
                    atomicAdd(&stats[2 * m], s);
                    atomicAdd(&stats[2 * m + 1], sq);
                }
            }
        }
    }
}

// ---------------- standalone GEMM (encoder / Wo / W2) ------------------------
// 512 blocks (M=4096/64 x N=512/64), XCD swizzle cpx=64.
__global__ __launch_bounds__(256) void mfma_gemm_kernel(
    const bf16* __restrict__ A, const bf16* __restrict__ Bt,
    const float* __restrict__ bias, const float* __restrict__ res,
    float* __restrict__ Cf, bf16* __restrict__ Cb,
    int K, int N, int act, float* stats)
{
    __shared__ short As[64 * 72];
    __shared__ short Bs[64 * 72];
    const int pid = blockIdx.x;                       // 0..511
    const int swz = ((pid & 7) << 6) | (pid >> 3);    // cpx = 64
    gemm64_body(As, Bs, A, Bt, (swz >> 3) * 64, (swz & 7) * 64, K, N,
                bias, res, Cf, Cb, act, stats);
}

// ---------------- W1 GEMM with inline LN on the A operand --------------------
// A = HB fp32 [4096][E]; per-row mean/rstd from the stats buffer filled by the
// Wo GEMM's epilogue (complete: prior dispatch). gamma/beta staged to LDS
// once. A-staging normalizes + casts to bf16 at the same rounding point the
// old ln_f32 kernel used, then the proven depth-1 schedule runs unchanged.
__global__ __launch_bounds__(256) void mfma_gemm_ln_kernel(
    const float* __restrict__ A, const bf16* __restrict__ Bt,
    const float* __restrict__ ST,
    const float* __restrict__ gam, const float* __restrict__ bet,
    const float* __restrict__ bias, bf16* __restrict__ Cb)
{
    __shared__ short As[64 * 72];
    __shared__ short Bs[64 * 72];
    __shared__ float gls[E], bls[E];
    const int pid = blockIdx.x;                       // 0..511
    const int swz = ((pid & 7) << 6) | (pid >> 3);    // cpx = 64
    const int m0 = (swz >> 3) * 64, n0 = (swz & 7) * 64;
    const int tid = threadIdx.x;
    // stage gamma/beta (512 floats each) to LDS
    *(float2*)&gls[tid * 2] = *(const float2*)&gam[tid * 2];
    *(float2*)&bls[tid * 2] = *(const float2*)&bet[tid * 2];

    const int w = tid >> 6, lane = tid & 63;
    const int wm2 = (w >> 1) * 32, wn2 = (w & 1) * 32;
    const int fr = lane & 15, quad = lane >> 4;

    const int arow = tid >> 2, acol = (tid & 3) * 16;  // 64 rows x 64 k
    const int g = m0 + arow;
    const float mean = ST[2 * g] * (1.0f / E);
    const float var  = ST[2 * g + 1] * (1.0f / E) - mean * mean;
    const float rstd = rsqrtf(var + 1e-6f);
    const float* Agf = A + (size_t)g * E + acol;
    const short* Bg = (const short*)Bt + (size_t)(n0 + arow) * E + acol;
    short* Asw = &As[arow * 72 + acol];
    short* Bsw = &Bs[arow * 72 + acol];

    frag_cd acc[2][2];
    #pragma unroll
    for (int i = 0; i < 2; ++i)
        #pragma unroll
        for (int j = 0; j < 2; ++j)
            acc[i][j] = (frag_cd)(0.0f);

    // prologue: stage regs for k0 = 0 (A in fp32)
    float4 f0 = *(const float4*)(Agf);
    float4 f1 = *(const float4*)(Agf + 4);
    float4 f2 = *(const float4*)(Agf + 8);
    float4 f3 = *(const float4*)(Agf + 12);
    uint4 b0 = *(const uint4*)(Bg);
    uint4 b1 = *(const uint4*)(Bg + 8);

    for (int k0 = 0; k0 < E; k0 += 64) {
        __syncthreads();                       // readers of previous tile done
        {   // normalize 16 elems -> bf16, write to LDS
            const float* gp = &gls[k0 + acol];
            const float* bp = &bls[k0 + acol];
            union { uint4 u; unsigned short s[8]; } p0, p1;
            p0.s[0] = f2bs((f0.x - mean) * rstd * gp[0]  + bp[0]);
            p0.s[1] = f2bs((f0.y - mean) * rstd * gp[1]  + bp[1]);
            p0.s[2] = f2bs((f0.z - mean) * rstd * gp[2]  + bp[2]);
            p0.s[3] = f2bs((f0.w - mean) * rstd * gp[3]  + bp[3]);
            p0.s[4] = f2bs((f1.x - mean) * rstd * gp[4]  + bp[4]);
            p0.s[5] = f2bs((f1.y - mean) * rstd * gp[5]  + bp[5]);
            p0.s[6] = f2bs((f1.z - mean) * rstd * gp[6]  + bp[6]);
            p0.s[7] = f2bs((f1.w - mean) * rstd * gp[7]  + bp[7]);
            p1.s[0] = f2bs((f2.x - mean) * rstd * gp[8]  + bp[8]);
            p1.s[1] = f2bs((f2.y - mean) * rstd * gp[9]  + bp[9]);
            p1.s[2] = f2bs((f2.z - mean) * rstd * gp[10] + bp[10]);
            p1.s[3] = f2bs((f2.w - mean) * rstd * gp[11] + bp[11]);
            p1.s[4] = f2bs((f3.x - mean) * rstd * gp[12] + bp[12]);
            p1.s[5] = f2bs((f3.y - mean) * rstd * gp[13] + bp[13]);
            p1.s[6] = f2bs((f3.z - mean) * rstd * gp[14] + bp[14]);
            p1.s[7] = f2bs((f3.w - mean) * rstd * gp[15] + bp[15]);
            *(uint4*)(Asw) = p0.u; *(uint4*)(Asw + 8) = p1.u;
        }
        *(uint4*)(Bsw) = b0; *(uint4*)(Bsw + 8) = b1;
        if (k0 + 64 < E) {                     // prefetch next tile -> regs
            f0 = *(const float4*)(Agf + k0 + 64);
            f1 = *(const float4*)(Agf + k0 + 68);
            f2 = *(const float4*)(Agf + k0 + 72);
            f3 = *(const float4*)(Agf + k0 + 76);
            b0 = *(const uint4*)(Bg + k0 + 64);
            b1 = *(const uint4*)(Bg + k0 + 72);
        }
        asm volatile("s_waitcnt lgkmcnt(0)" ::: "memory");  // LDS writes visible
        __builtin_amdgcn_s_barrier();                       // no vmcnt drain
        __builtin_amdgcn_sched_barrier(0);
        #pragma unroll
        for (int kh = 0; kh < 2; ++kh) {
            frag_ab af[2], bfr[2];
            #pragma unroll
            for (int i = 0; i < 2; ++i)
                af[i] = *(const frag_ab*)&As[(wm2 + i * 16 + fr) * 72 + kh * 32 + quad * 8];
            #pragma unroll
            for (int j = 0; j < 2; ++j)
                bfr[j] = *(const frag_ab*)&Bs[(wn2 + j * 16 + fr) * 72 + kh * 32 + quad * 8];
            #pragma unroll
            for (int i = 0; i < 2; ++i)
                #pragma unroll
                for (int j = 0; j < 2; ++j)
                    acc[i][j] = __builtin_amdgcn_mfma_f32_16x16x32_bf16(af[i], bfr[j], acc[i][j], 0, 0, 0);
        }
    }

    #pragma unroll
    for (int i = 0; i < 2; ++i) {
        #pragma unroll
        for (int r = 0; r < 4; ++r) {
            const int m = m0 + wm2 + i * 16 + quad * 4 + r;
            #pragma unroll
            for (int j = 0; j < 2; ++j) {
                const int n = n0 + wn2 + j * 16 + fr;
                const float v = gelu_tanh(acc[i][j][r] + bias[n]);
                Cb[(size_t)m * E + n] = __float2bfloat16(v);
            }
        }
    }
}

// ---------------- fused Q + KV + R projection (one dispatch) -----------------
__global__ __launch_bounds__(256) void qkvr_kernel(
    const bf16* __restrict__ QN, const bf16* __restrict__ VK,
    const bf16* __restrict__ PE_, const bf16* __restrict__ WqT,
    const bf16* __restrict__ WkvT, const bf16* __restrict__ WrT,
    const float* __restrict__ bq, const float* __restrict__ ub,
    const float* __restrict__ vbias, const float* __restrict__ bk,
    const float* __restrict__ bv,
    bf16* __restrict__ QU, bf16* __restrict__ QV,
    bf16* __restrict__ KB, bf16* __restrict__ VT, bf16* __restrict__ RB)
{
    __shared__ short As[128 * 72];
    __shared__ short Bs[64 * 72];
    const int bid = blockIdx.x;
    if (bid < 256) {
        const int swz = ((bid & 7) << 5) | (bid >> 3);        // cpx = 32
        gemm_body(As, Bs, QN, WqT, (swz >> 3) * 128, (swz & 7) * 64, E, E,
                  bq, ub, vbias, nullptr, nullptr, QU, QV, 0, 1);
    } else if (bid < 1280) {
        const int id = bid - 256;                              // 0..1023
        const int swz = ((id & 7) << 7) | (id >> 3);           // cpx = 128
        gemm_body(As, Bs, VK, WkvT, (swz >> 4) * 128, (swz & 15) * 64, E, 2 * E,
                  nullptr, bk, bv, nullptr, nullptr, KB, VT, 0, 2);
    } else {
        const int id = bid - 1280;                             // 0..63
        const int swz = ((id & 7) << 3) | (id >> 3);           // cpx = 8
        gemm_body(As, Bs, PE_, WrT, (swz >> 3) * 128, (swz & 7) * 64, E, E,
                  nullptr, nullptr, nullptr, nullptr, nullptr, RB, nullptr, 0, 0);
    }
}

// ---------------- merged LN pass 1 (memories + x) + stats zero ---------------
__global__ __launch_bounds__(256) void ln1_kernel(
    const float* __restrict__ mem, const float* __restrict__ X, int li,
    const float* __restrict__ gam, const float* __restrict__ bet,
    bf16* __restrict__ qn, bf16* __restrict__ vkdst, float* __restrict__ st)
{
    const int blk = blockIdx.x;
    const int t = threadIdx.x;
    if (blk < 32) st[blk * 256 + t] = 0.0f;   // zero 8192-float stats buffer
    const bool isMem = blk < B * MEM;
    const int rr = isMem ? blk : (blk - B * MEM);
    const float* sp = isMem ? (mem + ((size_t)rr * L + li) * E)
                            : (X + (size_t)rr * E);
    const float x0 = sp[t], x1 = sp[t + 256];
    float s = x0 + x1, ss = fmaf(x0, x0, x1 * x1);
    #pragma unroll
    for (int off = 32; off; off >>= 1) { s += __shfl_down(s, off, 64); ss += __shfl_down(ss, off, 64); }
    __shared__ float tmp[8];
    const int wid = t >> 6, lane = t & 63;
    if (!lane) { tmp[wid] = s; tmp[4 + wid] = ss; }
    __syncthreads();
    s = tmp[0] + tmp[1] + tmp[2] + tmp[3];
    ss = tmp[4] + tmp[5] + tmp[6] + tmp[7];
    const float mean = s * (1.0f / E);
    const float var = ss * (1.0f / E) - mean * mean;
    const float rstd = rsqrtf(var + 1e-6f);
    const float y0 = (x0 - mean) * rstd * gam[t] + bet[t];
    const float y1 = (x1 - mean) * rstd * gam[t + 256] + bet[t + 256];
    const int b = rr >> 9, p = rr & 511;
    if (isMem) {
        bf16* dst = vkdst + ((size_t)b * KLEN + p) * E;
        dst[t] = __float2bfloat16(y0); dst[t + 256] = __float2bfloat16(y1);
    } else {
        qn[(size_t)rr * E + t]       = __float2bfloat16(y0);
        qn[(size_t)rr * E + t + 256] = __float2bfloat16(y1);
        bf16* d2 = vkdst + ((size_t)b * KLEN + MEM + p) * E;
        d2[t] = __float2bfloat16(y0); d2[t + 256] = __float2bfloat16(y1);
    }
}

// ---------------- MFMA flash attention (swizzled LDS, defer-max) -------------
__global__ __launch_bounds__(256) void mfma_flash_kernel(
    const bf16* __restrict__ Qu,   // [B*S][E]  (pre-scaled by 1/8)
    const bf16* __restrict__ Qv,   // [B*S][E]  (pre-scaled by 1/8)
    const bf16* __restrict__ Kb,   // [B*KLEN][E]
    const bf16* __restrict__ Vt,   // [B][E][KLEN] (k' sigma-permuted per 64)
    const bf16* __restrict__ Rb,   // [KLEN][E]
    bf16* __restrict__ O)          // [B*S][E]
{
    const int pid = blockIdx.x;                       // 0..511
    const int swz = ((pid & 7) << 6) | (pid >> 3);    // cpx = 64; XCD x -> b = x
    const int qphys = swz & 7;
    const int hb = swz >> 3;
    const int h = hb & 7, b = hb >> 3;
    const int qt = (qphys & 1) ? (7 - (qphys >> 1)) : (qphys >> 1);
    const int q0 = qt * FQ;
    const int t = threadIdx.x;
    const int w = t >> 6, lane = t & 63;
    const int fr = lane & 15, quad = lane >> 4;
    const int qbase = q0 + w * 16;

    __shared__ short Ks[64 * 64];      // [k][e], swizzled
    __shared__ short Vs[64 * 64];      // [d][k'], swizzled
    __shared__ short Rs[128 * 64];     // circular R band, swizzled
    __shared__ short BDs[4 * 80 * 18]; // per-wave BD transposed [jlr][qw]
    __shared__ short Ps[4 * 16 * 64];  // per-wave P [q][k'], swizzled

    const int fxk = fr & 7;
    const int xq0 = (quad ^ fxk) << 3;          // cols 0..31  (chunk quad)
    const int xq1 = ((quad + 4) ^ fxk) << 3;    // cols 32..63 (chunk quad+4)

    // Q A-frags straight from global (one-time)
    const short* quptr = (const short*)Qu + ((size_t)(b * S + qbase + fr)) * E + h * DH + quad * 8;
    const frag_ab au0 = *(const frag_ab*)(quptr);
    const frag_ab au1 = *(const frag_ab*)(quptr + 32);
    const short* qvptr = (const short*)Qv + ((size_t)(b * S + qbase + fr)) * E + h * DH + quad * 8;
    const frag_ab av0 = *(const frag_ab*)(qvptr);
    const frag_ab av1 = *(const frag_ab*)(qvptr + 32);

    frag_cd accO[4];
    #pragma unroll
    for (int i = 0; i < 4; ++i) accO[i] = (frag_cd)(0.0f);
    float mrow[4] = {-3.0e38f, -3.0e38f, -3.0e38f, -3.0e38f};
    float lrow[4] = {0.f, 0.f, 0.f, 0.f};   // per-lane partial sums

    const int srow = t >> 2, scol = (t & 3) * 16;   // K/V staging
    const short* kg = (const short*)Kb + ((size_t)(b * KLEN + srow)) * E + h * DH + scol;
    const short* vg = (const short*)Vt + ((size_t)(b * E + h * DH + srow)) * KLEN + scol;
    const int sxs = srow & 7;
    const int scb = (t & 3) * 2;
    const int kvw0 = (srow << 6) + (((scb    ) ^ sxs) << 3);
    const int kvw1 = (srow << 6) + (((scb + 1) ^ sxs) << 3);
    const int ntb0 = 3 - w;            // wave BD window: n-tiles ntb0..ntb0+4
    const int b0 = 448 - q0;           // R band origin at kt=0 (0..448, mult of 64)

    // ---- initial R window: rows j = b0 .. b0+127 (always <= 575, no clamp) --
    {
        const int rr = t >> 1, rc = (t & 1) * 32;
        const int j = b0 + rr;
        const int slot = j & 127;
        const int sx = slot & 7, cb = rc >> 3;
        const short* rp = (const short*)Rb + (size_t)j * E + h * DH + rc;
        *(uint4*)&Rs[(slot << 6) + (((cb    ) ^ sx) << 3)] = *(const uint4*)(rp);
        *(uint4*)&Rs[(slot << 6) + (((cb + 1) ^ sx) << 3)] = *(const uint4*)(rp + 8);
        *(uint4*)&Rs[(slot << 6) + (((cb + 2) ^ sx) << 3)] = *(const uint4*)(rp + 16);
        *(uint4*)&Rs[(slot << 6) + (((cb + 3) ^ sx) << 3)] = *(const uint4*)(rp + 24);
    }

    const int ntiles = 9 + qt;

    // ---- prefetch registers ----
    const int r64 = t >> 2, rc4 = (t & 3) * 16;     // R slide staging
    uint4 ka0, ka1, va0, va1, ra0, ra1;
    int rslot = 0;
    {   // K/V tile 0
        ka0 = *(const uint4*)(kg);
        ka1 = *(const uint4*)(kg + 8);
        va0 = *(const uint4*)(vg);
        va1 = *(const uint4*)(vg + 8);
    }

    for (int kt = 0; kt < ntiles; ++kt) {
        const int k0 = kt * FK;
        __syncthreads();               // previous tile's readers done
        {   // stage K[64k][64e] and V^T[64d][64k'] from prefetched regs
            *(uint4*)&Ks[kvw0] = ka0;
            *(uint4*)&Ks[kvw1] = ka1;
            *(uint4*)&Vs[kvw0] = va0;
            *(uint4*)&Vs[kvw1] = va1;
        }
        if (kt >= 1) {   // slide R window: write 64 prefetched rows
            const int sx = rslot & 7;
            *(uint4*)&Rs[(rslot << 6) + (((scb    ) ^ sx) << 3)] = ra0;
            *(uint4*)&Rs[(rslot << 6) + (((scb + 1) ^ sx) << 3)] = ra1;
        }
        if (kt + 1 < ntiles) {         // prefetch next tile (hides under compute)
            const short* kp = kg + (size_t)(k0 + FK) * E;
            ka0 = *(const uint4*)(kp);
            ka1 = *(const uint4*)(kp + 8);
            const short* vp = vg + k0 + FK;
            va0 = *(const uint4*)(vp);
            va1 = *(const uint4*)(vp + 8);
            int j = b0 + 64 * (kt + 1) + 64 + r64;
            rslot = j & 127;
            if (j > KLEN - 1) j = KLEN - 1;   // clamped rows feed masked scores only
            const short* rp = (const short*)Rb + (size_t)j * E + h * DH + rc4;
            ra0 = *(const uint4*)(rp);
            ra1 = *(const uint4*)(rp + 8);
        }
        asm volatile("s_waitcnt lgkmcnt(0)" ::: "memory");   // LDS writes visible
        __builtin_amdgcn_s_barrier();                        // keep vmcnt in flight
        __builtin_amdgcn_sched_barrier(0);

        const int roff = (b0 + 64 * kt) & 127;   // band start slot (mult of 64)

        // ---- BD tile: BDs[w][jlr][qw] = Qv·R_band^T (wave's 80-col window) --
        __builtin_amdgcn_s_setprio(1);
        #pragma unroll
        for (int i = 0; i < 5; ++i) {
            const int ntb = ntb0 + i;
            const int slot = (roff + ntb * 16 + fr) & 127;   // slot&7 == fr&7
            const frag_ab rf0 = *(const frag_ab*)&Rs[(slot << 6) + xq0];
            const frag_ab rf1 = *(const frag_ab*)&Rs[(slot << 6) + xq1];
            frag_cd z = (frag_cd)(0.0f);
            z = __builtin_amdgcn_mfma_f32_16x16x32_bf16(av0, rf0, z, 0, 0, 0);
            z = __builtin_amdgcn_mfma_f32_16x16x32_bf16(av1, rf1, z, 0, 0, 0);
            union { unsigned u[2]; unsigned short sh[4]; } pk;
            pk.sh[0] = f2bs(z[0]); pk.sh[1] = f2bs(z[1]);
            pk.sh[2] = f2bs(z[2]); pk.sh[3] = f2bs(z[3]);
            const int bdw = (w * 80 + i * 16 + fr) * 18 + quad * 4;
            *(unsigned*)&BDs[bdw]     = pk.u[0];
            *(unsigned*)&BDs[bdw + 2] = pk.u[1];
        }

        // ---- S = Qu·K^T ----
        frag_cd sc[4];
        #pragma unroll
        for (int nt = 0; nt < 4; ++nt) {
            const int krow = (nt * 16 + fr) << 6;
            const frag_ab kf0 = *(const frag_ab*)&Ks[krow + xq0];
            const frag_ab kf1 = *(const frag_ab*)&Ks[krow + xq1];
            frag_cd z = (frag_cd)(0.0f);
            z = __builtin_amdgcn_mfma_f32_16x16x32_bf16(au0, kf0, z, 0, 0, 0);
            z = __builtin_amdgcn_mfma_f32_16x16x32_bf16(au1, kf1, z, 0, 0, 0);
            sc[nt] = z;
        }
        __builtin_amdgcn_s_setprio(0);

        // ---- +BD, mask (last tile only), defer-max online softmax ----
        const bool edge = (kt == ntiles - 1);   // only final tile crosses diagonal
        #pragma unroll
        for (int r = 0; r < 4; ++r) {
            const int qw = quad * 4 + r;
            float sv[4];
            #pragma unroll
            for (int nt = 0; nt < 4; ++nt) {
                const int jlr = nt * 16 + fr + 15 - qw;   // 0..78
                const float bd = bs2f(BDs[(w * 80 + jlr) * 18 + qw]);
                sv[nt] = sc[nt][r] + bd;                  // scale pre-folded into Q
            }
            if (edge) {
                const int qrow = qbase + qw;
                #pragma unroll
                for (int nt = 0; nt < 4; ++nt)
                    if (k0 + nt * 16 + fr > MEM + qrow) sv[nt] = -1e30f;
            }
            const float locmax = fmaxf(fmaxf(sv[0], sv[1]), fmaxf(sv[2], sv[3]));
            if (__any(locmax > mrow[r] + 4.0f)) {   // slow path (rare)
                float tm = locmax;
                tm = fmaxf(tm, __shfl_xor(tm, 1, 64));
                tm = fmaxf(tm, __shfl_xor(tm, 2, 64));
                tm = fmaxf(tm, __shfl_xor(tm, 4, 64));
                tm = fmaxf(tm, __shfl_xor(tm, 8, 64));
                const float mn = fmaxf(mrow[r], tm);
                const float al = __expf(mrow[r] - mn);
                lrow[r] *= al;
                #pragma unroll
                for (int nt = 0; nt < 4; ++nt) accO[nt][r] *= al;
                mrow[r] = mn;
            }
            const float p0 = __expf(sv[0] - mrow[r]), p1 = __expf(sv[1] - mrow[r]);
            const float p2 = __expf(sv[2] - mrow[r]), p3 = __expf(sv[3] - mrow[r]);
            lrow[r] += (p0 + p1) + (p2 + p3);       // per-lane partial
            union { uint2 u2; unsigned short sh[4]; } pq;
            pq.sh[0] = f2bs(p0); pq.sh[1] = f2bs(p1);
            pq.sh[2] = f2bs(p2); pq.sh[3] = f2bs(p3);
            // P[qw][k' = fr*4 .. fr*4+3] -> one aligned b64, swizzled chunk
            const int pw = (w << 10) + (qw << 6)
                         + (((fr >> 1) ^ (qw & 7)) << 3) + ((fr & 1) << 2);
            *(uint2*)&Ps[pw] = pq.u2;
        }

        // ---- O += P·V (per-wave P; same-wave LDS, DS in-order) ----
        const frag_ab pf0 = *(const frag_ab*)&Ps[(w << 10) + (fr << 6) + xq0];
        const frag_ab pf1 = *(const frag_ab*)&Ps[(w << 10) + (fr << 6) + xq1];
        __builtin_amdgcn_s_setprio(1);
        #pragma unroll
        for (int nt = 0; nt < 4; ++nt) {
            const int vrow = (nt * 16 + fr) << 6;
            const frag_ab vf0 = *(const frag_ab*)&Vs[vrow + xq0];
            const frag_ab vf1 = *(const frag_ab*)&Vs[vrow + xq1];
            accO[nt] = __builtin_amdgcn_mfma_f32_16x16x32_bf16(pf0, vf0, accO[nt], 0, 0, 0);
            accO[nt] = __builtin_amdgcn_mfma_f32_16x16x32_bf16(pf1, vf1, accO[nt], 0, 0, 0);
        }
        __builtin_amdgcn_s_setprio(0);
    }

    #pragma unroll
    for (int r = 0; r < 4; ++r) {
        float lsum = lrow[r];                    // reduce once, after the k-loop
        lsum += __shfl_xor(lsum, 1, 64);
        lsum += __shfl_xor(lsum, 2, 64);
        lsum += __shfl_xor(lsum, 4, 64);
        lsum += __shfl_xor(lsum, 8, 64);
        const float inv = 1.0f / lsum;
        bf16* po = O + ((size_t)(b * S + qbase + quad * 4 + r)) * E + h * DH + fr;
        #pragma unroll
        for (int nt = 0; nt < 4; ++nt)
            po[nt * 16] = __float2bfloat16(accO[nt][r] * inv);
    }
}

extern "C" void kernel_launch(void* const* d_in, const int* in_sizes, int n_in,
                              void* d_out, int out_size, void* d_ws, size_t ws_size,
                              hipStream_t stream)
{
    const float* obs  = (const float*)d_in[0];
    const float* mem  = (const float*)d_in[1];
    // d_in[2] = mask: deterministic (k <= MEM + q), recomputed in-kernel
    const float* Wenc = (const float*)d_in[3];
    const float* benc = (const float*)d_in[4];
    const float* ln1s = (const float*)d_in[5];
    const float* ln1b = (const float*)d_in[6];
    const float* Wq   = (const float*)d_in[7];
    const float* bq   = (const float*)d_in[8];
    const float* Wk   = (const float*)d_in[9];
    const float* bk   = (const float*)d_in[10];
    const float* Wv   = (const float*)d_in[11];
    const float* bv   = (const float*)d_in[12];
    const float* Wr   = (const float*)d_in[13];
    const float* ub   = (const float*)d_in[14];
    const float* vb   = (const float*)d_in[15];
    const float* Wo   = (const float*)d_in[16];
    const float* bo   = (const float*)d_in[17];
    const float* ln2s = (const float*)d_in[18];
    const float* ln2b = (const float*)d_in[19];
    const float* W1   = (const float*)d_in[20];
    const float* b1   = (const float*)d_in[21];
    const float* W2   = (const float*)d_in[22];
    const float* b2   = (const float*)d_in[23];

    // ---- workspace ----
    float* wsf = (float*)d_ws;
    float* X = wsf;                                   // fp32 [B*S*E]
    bf16* wsb = (bf16*)(wsf + (size_t)B * S * E);
    size_t ob = 0;
    bf16* OBSb = wsb + ob; ob += (size_t)B * S * OBS;
    bf16* QNb  = wsb + ob; ob += (size_t)B * S * E;
    bf16* PEb  = wsb + ob; ob += (size_t)KLEN * E;
    bf16* RBb  = wsb + ob; ob += (size_t)KLEN * E;
    bf16* WencT= wsb + ob; ob += (size_t)OBS * E;
    bf16* WqT  = wsb + ob; ob += (size_t)L * E * E;
    bf16* WkvT = wsb + ob; ob += (size_t)L * 2 * E * E;   // [L][1024][512]
    bf16* WrT  = wsb + ob; ob += (size_t)L * E * E;
    bf16* WoT  = wsb + ob; ob += (size_t)L * E * E;
    bf16* W1T  = wsb + ob; ob += (size_t)L * E * E;
    bf16* W2T  = wsb + ob; ob += (size_t)L * E * E;
    bf16* QUb  = wsb + ob; ob += (size_t)B * S * E;
    bf16* QVb  = wsb + ob; ob += (size_t)B * S * E;
    bf16* KBb  = wsb + ob; ob += (size_t)B * KLEN * E;
    bf16* VTb  = wsb + ob; ob += (size_t)B * E * KLEN;
    bf16* OBb  = wsb + ob; ob += (size_t)B * S * E;
    float* ST  = (float*)(wsb + ob); ob += 16384;     // [4096][2] row stats (32KB)
    // union: {VKb} ∪ {HB, FFb} (disjoint lifetimes per layer)
    char* uni = (char*)(wsb + ob);
    bf16*  VKb = (bf16*)uni;                          // [B*KLEN][E] (8 MB) @0
    float* HB  = (float*)uni;                         // [B*S][E] fp32 (8 MB) @0
    bf16*  FFb = (bf16*)(uni + ((size_t)8 << 20));    // [B*S][E] (4 MB) @8M

    // NOTE: VKb (qkvr input) and HB (Wo output) share @0 — lifetimes disjoint:
    // VKb live ln1->qkvr; HB live Wo-gemm->W2-gemm. qkvr finishes before Wo runs.

    // ---- setup: merged weight transposes, obs cast + pe ----
    transpose_all_kernel<<<dim3(E / 32, E / 32, 29), 256, 0, stream>>>(
        Wq, Wk, Wv, Wr, Wo, W1, W2, Wenc, WqT, WkvT, WrT, WoT, W1T, W2T, WencT);
    setup_kernel<<<(B * S * OBS + KLEN * E) / 256, 256, 0, stream>>>(obs, OBSb, PEb);

    // encoder: X = obs @ W_enc + b_enc (fp32)
    mfma_gemm_kernel<<<512, 256, 0, stream>>>(
        OBSb, WencT, benc, nullptr, X, nullptr, OBS, E, 0, nullptr);

    for (int li = 0; li < L; ++li) {
        const size_t wOff = (size_t)li * E * E;
        const size_t vOff = (size_t)li * E;

        ln1_kernel<<<2 * B * S, 256, 0, stream>>>(
            mem, X, li, ln1s + vOff, ln1b + vOff, QNb, VKb, ST);

        // qkvr writes V directly transposed to VTb (no transpose_v kernel)
        qkvr_kernel<<<1344, 256, 0, stream>>>(
            QNb, VKb, PEb, WqT + wOff, WkvT + (size_t)li * 2 * E * E, WrT + wOff,
            bq + vOff, ub + vOff, vb + vOff, bk + vOff, bv + vOff,
            QUb, QVb, KBb, VTb, RBb);

        mfma_flash_kernel<<<512, 256, 0, stream>>>(
            QUb, QVb, KBb, VTb, RBb, OBb);

        // HB = X + (O @ Wo + bo); epilogue accumulates per-row LN stats -> ST
        mfma_gemm_kernel<<<512, 256, 0, stream>>>(
            OBb, WoT + wOff, bo + vOff, X, HB, nullptr, E, E, 0, ST);
        // FFb = gelu(LN(HB) @ W1 + b1)  -- inline LN, replaces ln_f32 kernel
        mfma_gemm_ln_kernel<<<512, 256, 0, stream>>>(
            HB, W1T + wOff, ST, ln2s + vOff, ln2b + vOff, b1 + vOff, FFb);
        // X = FF @ W2 + b2 + HB   (last layer writes d_out directly)
        float* dst = (li == L - 1) ? (float*)d_out : X;
        mfma_gemm_kernel<<<512, 256, 0, stream>>>(
            FFb, W2T + wOff, b2 + vOff, HB, dst, nullptr, E, E, 0, nullptr);
    }
}